// Round 1
// baseline (1372.958 us; speedup 1.0000x reference)
//
#include <hip/hip_runtime.h>
#include <hip/hip_bf16.h>
#include <math.h>

// ProGAT: B=32, S=512, K=21, F_in=26, E=256, R=3, T=2
// All fp32. Kernel plan:
//   embed        : amino_feature (-> h) and nf_all from F_in=26 inputs
//   per round d:
//     rowdots    : ca[row]=cur.w1, cb[row]=nbrsrc.w2  (alignment score halves)
//     gemm       : act_t = nbrsrc @ attend_W[d].T + attend_b[d]
//     attn       : per (b,s): softmax over 21 neighbors, gather act_t rows -> context (elu)
//     gemm x2    : gi = context @ wih.T + bih ; gh = h @ whh.T + bhh
//     gru_gate   : h = (1-z)n + z h ; act = relu(h)
//   seqpool      : seq_feature = sum_s act*mask ; act_mol = relu ; moldot = act_mol . saW[:256]
//   seqscore     : per row: leaky(moldot + act.saW[256:] + b) + mask NEG
//   gemm         : feat_t = act @ seq_attend_W.T + b
//   seqctx       : per b: softmax over S, weighted sum of feat_t -> elu  (loop-invariant, once)
//   sgru x2      : small GRU on (32,256)

#define NEGC (-9.0e8f)

__global__ __launch_bounds__(256) void embed_kernel(
    const float* __restrict__ amino, const float* __restrict__ embW,
    const float* __restrict__ embB, const float* __restrict__ neighW,
    const float* __restrict__ neighB,
    float* __restrict__ h, float* __restrict__ nf)
{
    const int FIN = 26;
    __shared__ float wE[26][256];
    __shared__ float wN[26][256];
    __shared__ float xs[16][26];
    int tid = threadIdx.x;
    for (int idx = tid; idx < FIN*256; idx += 256) {
        int e = idx / FIN, f = idx - e*FIN;
        wE[f][e] = embW[idx];
        wN[f][e] = neighW[idx];
    }
    int row0 = blockIdx.x * 16;
    for (int idx = tid; idx < 16*FIN; idx += 256) {
        int r = idx / FIN, f = idx - r*FIN;
        xs[r][f] = amino[(size_t)(row0 + r)*FIN + f];
    }
    __syncthreads();
    float acc1[16], acc2[16];
    float b1 = embB[tid], b2 = neighB[tid];
#pragma unroll
    for (int r = 0; r < 16; ++r) { acc1[r] = b1; acc2[r] = b2; }
    for (int f = 0; f < FIN; ++f) {
        float we = wE[f][tid], wn = wN[f][tid];
#pragma unroll
        for (int r = 0; r < 16; ++r) {
            float x = xs[r][f];
            acc1[r] = fmaf(x, we, acc1[r]);
            acc2[r] = fmaf(x, wn, acc2[r]);
        }
    }
#pragma unroll
    for (int r = 0; r < 16; ++r) {
        float a = acc1[r]; a = a > 0.f ? a : 0.01f*a;
        float c = acc2[r]; c = c > 0.f ? c : 0.01f*c;
        h [(size_t)(row0+r)*256 + tid] = a;
        nf[(size_t)(row0+r)*256 + tid] = c;
    }
}

// C[M,N] = A[M,K] @ W[N,K]^T + bias[N]   (K multiple of 32, M,N multiples of 64)
__global__ __launch_bounds__(256) void gemm_bias_kernel(
    const float* __restrict__ A, const float* __restrict__ W,
    const float* __restrict__ bias, float* __restrict__ C,
    int M, int N, int K)
{
    __shared__ float As[64][33];
    __shared__ float Ws[64][33];
    int tid = threadIdx.x;
    int bm = blockIdx.x * 64;
    int bn = blockIdx.y * 64;
    int tx = tid & 15, ty = tid >> 4;
    float acc[4][4] = {};
    for (int k0 = 0; k0 < K; k0 += 32) {
#pragma unroll
        for (int l = 0; l < 2; ++l) {
            int idx = tid + l*256;
            int row = idx >> 3;
            int c4 = (idx & 7) << 2;
            float4 av = *reinterpret_cast<const float4*>(&A[(size_t)(bm+row)*K + k0 + c4]);
            As[row][c4] = av.x; As[row][c4+1] = av.y; As[row][c4+2] = av.z; As[row][c4+3] = av.w;
            float4 wv = *reinterpret_cast<const float4*>(&W[(size_t)(bn+row)*K + k0 + c4]);
            Ws[row][c4] = wv.x; Ws[row][c4+1] = wv.y; Ws[row][c4+2] = wv.z; Ws[row][c4+3] = wv.w;
        }
        __syncthreads();
#pragma unroll
        for (int k = 0; k < 32; ++k) {
            float a[4], w[4];
#pragma unroll
            for (int i = 0; i < 4; ++i) a[i] = As[ty*4+i][k];
#pragma unroll
            for (int j = 0; j < 4; ++j) w[j] = Ws[tx*4+j][k];
#pragma unroll
            for (int i = 0; i < 4; ++i)
#pragma unroll
                for (int j = 0; j < 4; ++j)
                    acc[i][j] = fmaf(a[i], w[j], acc[i][j]);
        }
        __syncthreads();
    }
#pragma unroll
    for (int i = 0; i < 4; ++i) {
        int r = bm + ty*4 + i;
        int cb = bn + tx*4;
        float4 o;
        o.x = acc[i][0] + bias[cb];
        o.y = acc[i][1] + bias[cb+1];
        o.z = acc[i][2] + bias[cb+2];
        o.w = acc[i][3] + bias[cb+3];
        *reinterpret_cast<float4*>(&C[(size_t)r*N + cb]) = o;
    }
}

// ca[row] = cur[row,:] . w1 ; cb[row] = nbr[row,:] . w2   (w = alignW: 512 floats)
__global__ __launch_bounds__(256) void rowdots_kernel(
    const float* __restrict__ cur, const float* __restrict__ nbr,
    const float* __restrict__ alignW,
    float* __restrict__ ca, float* __restrict__ cb)
{
    int row = blockIdx.x*4 + (threadIdx.x >> 6);
    int lane = threadIdx.x & 63;
    const float* c = cur + (size_t)row*256;
    const float* n = nbr + (size_t)row*256;
    float p1 = 0.f, p2 = 0.f;
#pragma unroll
    for (int i = 0; i < 4; ++i) {
        int idx = lane + 64*i;
        p1 = fmaf(c[idx], alignW[idx], p1);
        p2 = fmaf(n[idx], alignW[256+idx], p2);
    }
#pragma unroll
    for (int off = 32; off > 0; off >>= 1) {
        p1 += __shfl_down(p1, off);
        p2 += __shfl_down(p2, off);
    }
    if (lane == 0) { ca[row] = p1; cb[row] = p2; }
}

// per (b,s): neighbor softmax over K=21, context = elu(sum_k w_k * act_t[b, j_k, :])
__global__ __launch_bounds__(256) void attn_kernel(
    const int* __restrict__ deg, const float* __restrict__ ca,
    const float* __restrict__ cbrow, const float* __restrict__ act_t,
    const float* __restrict__ alignB, int d,
    float* __restrict__ context, int S)
{
    const int KNB = 21;
    int bs = blockIdx.x;
    int b = bs >> 9;   // S = 512
    int tid = threadIdx.x;
    __shared__ float ss[KNB];   // scores
    __shared__ float se[KNB];   // exp(score - max)
    __shared__ int   sj[KNB];
    if (tid < KNB) {
        int j = deg[bs*KNB + tid];
        float cbv = (j >= 0) ? cbrow[b*S + j] : 0.f;
        float sc = ca[bs] + cbv + alignB[d];
        sc = sc > 0.f ? sc : 0.01f*sc;
        if (j < 0) sc += NEGC;
        sj[tid] = j;
        ss[tid] = sc;
    }
    __syncthreads();
    float mx = -3.4e38f;
#pragma unroll
    for (int k = 0; k < KNB; ++k) mx = fmaxf(mx, ss[k]);
    __syncthreads();
    if (tid < KNB) se[tid] = expf(ss[tid] - mx);
    __syncthreads();
    float sum = 0.f;
#pragma unroll
    for (int k = 0; k < KNB; ++k) sum += se[k];
    float inv = 1.f / sum;
    float acc = 0.f;
#pragma unroll
    for (int k = 0; k < KNB; ++k) {
        int j = sj[k];
        if (j >= 0)
            acc = fmaf(se[k], act_t[((size_t)b*S + j)*256 + tid], acc);
    }
    acc *= inv;
    context[(size_t)bs*256 + tid] = acc > 0.f ? acc : expm1f(acc);
}

__global__ __launch_bounds__(256) void gru_gate_kernel(
    const float* __restrict__ gi, const float* __restrict__ gh,
    float* __restrict__ h, float* __restrict__ act)
{
    int row = blockIdx.x;
    int e = threadIdx.x;
    const float* gir = gi + (size_t)row*768;
    const float* ghr = gh + (size_t)row*768;
    float r = 1.f/(1.f + expf(-(gir[e]     + ghr[e])));
    float z = 1.f/(1.f + expf(-(gir[e+256] + ghr[e+256])));
    float n = tanhf(gir[e+512] + r*ghr[e+512]);
    size_t idx = (size_t)row*256 + e;
    float hv = h[idx];
    float hn = (1.f - z)*n + z*hv;
    h[idx] = hn;
    act[idx] = fmaxf(hn, 0.f);
}

__global__ __launch_bounds__(256) void seqpool_kernel(
    const float* __restrict__ act, const float* __restrict__ mask,
    const float* __restrict__ saW, float* __restrict__ seqfeat,
    float* __restrict__ actmol, float* __restrict__ moldot, int S)
{
    int b = blockIdx.x, tid = threadIdx.x;
    int lane = tid & 63, wv = tid >> 6;
    __shared__ float red[4];
    const float* ab = act + (size_t)b*S*256;
    const float* mb = mask + b*S;
    float acc = 0.f;
    for (int s = 0; s < S; ++s)
        acc = fmaf(ab[(size_t)s*256 + tid], mb[s], acc);
    seqfeat[b*256 + tid] = acc;
    float am = fmaxf(acc, 0.f);
    actmol[b*256 + tid] = am;
    float p = am * saW[tid];
#pragma unroll
    for (int off = 32; off > 0; off >>= 1) p += __shfl_down(p, off);
    if (lane == 0) red[wv] = p;
    __syncthreads();
    if (tid == 0) moldot[b] = red[0]+red[1]+red[2]+red[3];
}

__global__ __launch_bounds__(256) void seqscore_kernel(
    const float* __restrict__ act, const float* __restrict__ saW,
    const float* __restrict__ sab, const float* __restrict__ moldot,
    const float* __restrict__ mask, float* __restrict__ score, int S)
{
    int row = blockIdx.x*4 + (threadIdx.x >> 6);
    int lane = threadIdx.x & 63;
    int b = row / S;
    const float* a = act + (size_t)row*256;
    float p = 0.f;
#pragma unroll
    for (int i = 0; i < 4; ++i) {
        int idx = lane + 64*i;
        p = fmaf(a[idx], saW[256+idx], p);
    }
#pragma unroll
    for (int off = 32; off > 0; off >>= 1) p += __shfl_down(p, off);
    if (lane == 0) {
        float sc = moldot[b] + p + sab[0];
        sc = sc > 0.f ? sc : 0.01f*sc;
        if (mask[row] == 0.f) sc += NEGC;
        score[row] = sc;
    }
}

__global__ __launch_bounds__(256) void seqctx_kernel(
    const float* __restrict__ score, const float* __restrict__ mask,
    const float* __restrict__ feat, float* __restrict__ seqctx, int S)
{
    int b = blockIdx.x;
    int tid = threadIdx.x;
    int lane = tid & 63, wv = tid >> 6;
    __shared__ float sw[512];
    __shared__ float r1[4], r2[4];
    float lm = -3.4e38f;
    for (int s = tid; s < S; s += 256) {
        float v = score[b*S + s];
        sw[s] = v;
        lm = fmaxf(lm, v);
    }
#pragma unroll
    for (int off = 32; off > 0; off >>= 1) lm = fmaxf(lm, __shfl_down(lm, off));
    if (lane == 0) r1[wv] = lm;
    __syncthreads();
    float mx = fmaxf(fmaxf(r1[0], r1[1]), fmaxf(r1[2], r1[3]));
    float ls = 0.f;
    for (int s = tid; s < S; s += 256) {
        float e = expf(sw[s] - mx);
        sw[s] = e * mask[b*S + s];
        ls += e;
    }
#pragma unroll
    for (int off = 32; off > 0; off >>= 1) ls += __shfl_down(ls, off);
    if (lane == 0) r2[wv] = ls;
    __syncthreads();
    float inv = 1.f / (r2[0]+r2[1]+r2[2]+r2[3]);
    float acc = 0.f;
    for (int s = 0; s < S; ++s)
        acc = fmaf(sw[s], feat[((size_t)b*S + s)*256 + tid], acc);
    acc *= inv;
    seqctx[b*256 + tid] = acc > 0.f ? acc : expm1f(acc);
}

// small GRU matmuls: g[b*1536 + j] ; j<768 -> gi from x, else gh from hseq
__global__ __launch_bounds__(256) void sgru_mm_kernel(
    const float* __restrict__ x, const float* __restrict__ hseq,
    const float* __restrict__ wih, const float* __restrict__ whh,
    const float* __restrict__ bih, const float* __restrict__ bhh,
    float* __restrict__ g)
{
    int out = blockIdx.x*4 + (threadIdx.x >> 6);
    int lane = threadIdx.x & 63;
    int b = out / 1536;
    int j = out - b*1536;
    const float* src; const float* w; const float* bp; int jj;
    if (j < 768) { src = x    + b*256; w = wih; bp = bih; jj = j; }
    else         { src = hseq + b*256; w = whh; bp = bhh; jj = j - 768; }
    float p = 0.f;
#pragma unroll
    for (int i = 0; i < 4; ++i) {
        int idx = lane + 64*i;
        p = fmaf(src[idx], w[(size_t)jj*256 + idx], p);
    }
#pragma unroll
    for (int off = 32; off > 0; off >>= 1) p += __shfl_down(p, off);
    if (lane == 0) g[out] = p + bp[jj];
}

__global__ __launch_bounds__(256) void sgru_gate_kernel(
    const float* __restrict__ g, float* __restrict__ hseq, float* __restrict__ out)
{
    int b = blockIdx.x, e = threadIdx.x;
    const float* gr = g + b*1536;
    float r = 1.f/(1.f + expf(-(gr[e]     + gr[768+e])));
    float z = 1.f/(1.f + expf(-(gr[256+e] + gr[1024+e])));
    float n = tanhf(gr[512+e] + r*gr[1280+e]);
    float hv = hseq[b*256 + e];
    float hn = (1.f - z)*n + z*hv;
    hseq[b*256 + e] = hn;
    out[b*256 + e] = fmaxf(hn, 0.f);
}

extern "C" void kernel_launch(void* const* d_in, const int* in_sizes, int n_in,
                              void* d_out, int out_size, void* d_ws, size_t ws_size,
                              hipStream_t stream)
{
    const float* amino   = (const float*)d_in[0];
    const int*   deg     = (const int*)  d_in[1];
    const float* mask    = (const float*)d_in[2];
    const float* embW    = (const float*)d_in[3];
    const float* embB    = (const float*)d_in[4];
    const float* neighW  = (const float*)d_in[5];
    const float* neighB  = (const float*)d_in[6];
    const float* alignW  = (const float*)d_in[7];
    const float* alignB  = (const float*)d_in[8];
    const float* attendW = (const float*)d_in[9];
    const float* attendB = (const float*)d_in[10];
    const float* gruWih  = (const float*)d_in[11];
    const float* gruWhh  = (const float*)d_in[12];
    const float* gruBih  = (const float*)d_in[13];
    const float* gruBhh  = (const float*)d_in[14];
    const float* saW     = (const float*)d_in[15];
    const float* saB     = (const float*)d_in[16];
    const float* seqAttW = (const float*)d_in[17];
    const float* seqAttB = (const float*)d_in[18];
    const float* sWih    = (const float*)d_in[19];
    const float* sWhh    = (const float*)d_in[20];
    const float* sBih    = (const float*)d_in[21];
    const float* sBhh    = (const float*)d_in[22];
    float* out = (float*)d_out;

    const int B = 32, S = 512;
    const int BS = B*S;              // 16384

    // workspace layout (floats): ~168 MB total
    float* ws   = (float*)d_ws;
    float* h    = ws;                              // BS*256 (amino_feature / GRU h)
    float* act  = h   + (size_t)BS*256;            // BS*256 (relu(h))
    float* ctx  = act + (size_t)BS*256;            // BS*256 (nf_all, then context per round)
    float* attb = ctx + (size_t)BS*256;            // BS*256 (act_t / feat_t)
    float* gi   = attb+ (size_t)BS*256;            // BS*768
    float* gh   = gi  + (size_t)BS*768;            // BS*768
    float* ca   = gh  + (size_t)BS*768;            // BS
    float* cb   = ca  + BS;                        // BS
    float* scor = cb  + BS;                        // BS
    float* seqf = scor+ BS;                        // B*256
    float* amol = seqf+ B*256;                     // B*256
    float* mdot = amol+ B*256;                     // B
    float* sctx = mdot+ 1024;                      // B*256
    float* g    = sctx+ B*256;                     // B*1536

    // h = amino_feature, ctx = nf_all
    embed_kernel<<<BS/16, 256, 0, stream>>>(amino, embW, embB, neighW, neighB, h, ctx);

    for (int d = 0; d < 3; ++d) {
        const float* cur    = (d == 0) ? h   : act;
        const float* nbrsrc = (d == 0) ? ctx : act;
        rowdots_kernel<<<BS/4, 256, 0, stream>>>(cur, nbrsrc, alignW + d*512, ca, cb);
        dim3 g1(BS/64, 256/64);
        gemm_bias_kernel<<<g1, 256, 0, stream>>>(nbrsrc, attendW + d*256*256,
                                                 attendB + d*256, attb, BS, 256, 256);
        attn_kernel<<<BS, 256, 0, stream>>>(deg, ca, cb, attb, alignB, d, ctx, S);
        dim3 g2(BS/64, 768/64);
        gemm_bias_kernel<<<g2, 256, 0, stream>>>(ctx, gruWih + d*768*256,
                                                 gruBih + d*768, gi, BS, 768, 256);
        gemm_bias_kernel<<<g2, 256, 0, stream>>>(h,   gruWhh + d*768*256,
                                                 gruBhh + d*768, gh, BS, 768, 256);
        gru_gate_kernel<<<BS, 256, 0, stream>>>(gi, gh, h, act);
    }

    seqpool_kernel<<<B, 256, 0, stream>>>(act, mask, saW, seqf, amol, mdot, S);
    seqscore_kernel<<<BS/4, 256, 0, stream>>>(act, saW, saB, mdot, mask, scor, S);
    dim3 g3(BS/64, 256/64);
    gemm_bias_kernel<<<g3, 256, 0, stream>>>(act, seqAttW, seqAttB, attb, BS, 256, 256);
    seqctx_kernel<<<B, 256, 0, stream>>>(scor, mask, attb, sctx, S);

    for (int t = 0; t < 2; ++t) {
        sgru_mm_kernel<<<B*1536/4, 256, 0, stream>>>(sctx, seqf, sWih, sWhh, sBih, sBhh, g);
        sgru_gate_kernel<<<B, 256, 0, stream>>>(g, seqf, out);
    }
}

// Round 2
// 630.245 us; speedup vs baseline: 2.1785x; 2.1785x over previous
//
#include <hip/hip_runtime.h>
#include <hip/hip_bf16.h>
#include <math.h>

// ProGAT: B=32, S=512, K=21, F_in=26, E=256, R=3, T=2
// Round 1: all big GEMMs (A @ W^T + b) moved to bf16 MFMA (16x16x32), m97 structure:
//   128x128 tile, BK=32, 4 waves (2x2), 4x4 fragments/wave, global_load_lds width=16.
// Producers dual-write bf16 activation mirrors; weights converted to bf16 once per launch.

#define NEGC (-9.0e8f)

typedef __attribute__((ext_vector_type(8))) short bf16x8;
typedef __attribute__((ext_vector_type(4))) float f32x4;

__device__ __forceinline__ ushort f2bf(float x) {
    union { float f; unsigned u; } v; v.f = x;
    unsigned r = v.u + 0x7FFF + ((v.u >> 16) & 1);   // round-nearest-even
    return (ushort)(r >> 16);
}
__device__ __forceinline__ float bf2f(ushort u) {
    union { unsigned u; float f; } v; v.u = ((unsigned)u) << 16;
    return v.f;
}

typedef const __attribute__((address_space(1))) void gvoid_t;
typedef __attribute__((address_space(3))) void lvoid_t;

__global__ __launch_bounds__(256) void cvt_kernel(const float* __restrict__ src,
                                                  ushort* __restrict__ dst, int n4)
{
    int i = blockIdx.x * 256 + threadIdx.x;
    if (i < n4) {
        float4 v = *reinterpret_cast<const float4*>(&src[i * 4]);
        ushort4 o;
        o.x = f2bf(v.x); o.y = f2bf(v.y); o.z = f2bf(v.z); o.w = f2bf(v.w);
        *reinterpret_cast<ushort4*>(&dst[i * 4]) = o;
    }
}

// ---------------- bf16 MFMA GEMM: C[M,N] = A[M,K] @ W[N,K]^T + bias ----------------
// A, W bf16 row-major; writes Cf (fp32) and/or Cb (bf16). M%128==0, N%128==0, K%32==0.
__global__ __launch_bounds__(256) void gemm_mfma_kernel(
    const ushort* __restrict__ A, const ushort* __restrict__ W,
    const float* __restrict__ bias, float* __restrict__ Cf,
    ushort* __restrict__ Cb, int M, int N, int K)
{
    __shared__ __align__(16) short As[128 * 32];
    __shared__ __align__(16) short Bs[128 * 32];
    int tid = threadIdx.x;
    int lane = tid & 63;
    int w = tid >> 6;
    int wr = w >> 1, wc = w & 1;
    int bm = blockIdx.x * 128;
    int bn = blockIdx.y * 128;

    f32x4 acc[4][4];
#pragma unroll
    for (int m = 0; m < 4; ++m)
#pragma unroll
        for (int n = 0; n < 4; ++n) acc[m][n] = (f32x4){0.f, 0.f, 0.f, 0.f};

    for (int k0 = 0; k0 < K; k0 += 32) {
        // stage 128x32 A-tile and B-tile: per wave 2 chunks of 1KB each (lane*16B appended by HW)
#pragma unroll
        for (int i = 0; i < 2; ++i) {
            int e = w * 1024 + i * 512 + lane * 8;   // element index in [128][32] tile
            int r = e >> 5, c = e & 31;
            const ushort* ga = A + (size_t)(bm + r) * K + (k0 + c);
            const ushort* gw = W + (size_t)(bn + r) * K + (k0 + c);
            __builtin_amdgcn_global_load_lds((gvoid_t*)ga, (lvoid_t*)&As[w * 1024 + i * 512], 16, 0, 0);
            __builtin_amdgcn_global_load_lds((gvoid_t*)gw, (lvoid_t*)&Bs[w * 1024 + i * 512], 16, 0, 0);
        }
        __syncthreads();
        bf16x8 af[4], bw[4];
        int ra = wr * 64 + (lane & 15);
        int rb = wc * 64 + (lane & 15);
        int kc = (lane >> 4) * 8;
#pragma unroll
        for (int m = 0; m < 4; ++m)
            af[m] = *reinterpret_cast<const bf16x8*>(&As[(ra + m * 16) * 32 + kc]);
#pragma unroll
        for (int n = 0; n < 4; ++n)
            bw[n] = *reinterpret_cast<const bf16x8*>(&Bs[(rb + n * 16) * 32 + kc]);
#pragma unroll
        for (int m = 0; m < 4; ++m)
#pragma unroll
            for (int n = 0; n < 4; ++n)
                acc[m][n] = __builtin_amdgcn_mfma_f32_16x16x32_bf16(af[m], bw[n], acc[m][n], 0, 0, 0);
        __syncthreads();
    }

    // epilogue: C/D layout col=lane&15, row=(lane>>4)*4+j
    int cr0 = bm + wr * 64 + ((lane >> 4) * 4);
    int cc0 = bn + wc * 64 + (lane & 15);
#pragma unroll
    for (int n = 0; n < 4; ++n) {
        int col = cc0 + n * 16;
        float bv = bias[col];
#pragma unroll
        for (int m = 0; m < 4; ++m) {
            int row0 = cr0 + m * 16;
#pragma unroll
            for (int j = 0; j < 4; ++j) {
                float v = acc[m][n][j] + bv;
                size_t idx = (size_t)(row0 + j) * N + col;
                if (Cf) Cf[idx] = v;
                if (Cb) Cb[idx] = f2bf(v);
            }
        }
    }
}

// ---------------- embed: h = leaky(amino@embW.T+b), nf = leaky(amino@neighW.T+b) ----
__global__ __launch_bounds__(256) void embed_kernel(
    const float* __restrict__ amino, const float* __restrict__ embW,
    const float* __restrict__ embB, const float* __restrict__ neighW,
    const float* __restrict__ neighB,
    float* __restrict__ h, float* __restrict__ nf,
    ushort* __restrict__ h_bf, ushort* __restrict__ nf_bf)
{
    const int FIN = 26;
    __shared__ float wE[26][256];
    __shared__ float wN[26][256];
    __shared__ float xs[16][26];
    int tid = threadIdx.x;
    for (int idx = tid; idx < FIN * 256; idx += 256) {
        int e = idx / FIN, f = idx - e * FIN;
        wE[f][e] = embW[idx];
        wN[f][e] = neighW[idx];
    }
    int row0 = blockIdx.x * 16;
    for (int idx = tid; idx < 16 * FIN; idx += 256) {
        int r = idx / FIN, f = idx - r * FIN;
        xs[r][f] = amino[(size_t)(row0 + r) * FIN + f];
    }
    __syncthreads();
    float acc1[16], acc2[16];
    float b1 = embB[tid], b2 = neighB[tid];
#pragma unroll
    for (int r = 0; r < 16; ++r) { acc1[r] = b1; acc2[r] = b2; }
    for (int f = 0; f < FIN; ++f) {
        float we = wE[f][tid], wn = wN[f][tid];
#pragma unroll
        for (int r = 0; r < 16; ++r) {
            float x = xs[r][f];
            acc1[r] = fmaf(x, we, acc1[r]);
            acc2[r] = fmaf(x, wn, acc2[r]);
        }
    }
#pragma unroll
    for (int r = 0; r < 16; ++r) {
        float a = acc1[r]; a = a > 0.f ? a : 0.01f * a;
        float c = acc2[r]; c = c > 0.f ? c : 0.01f * c;
        size_t idx = (size_t)(row0 + r) * 256 + tid;
        h[idx] = a;  h_bf[idx] = f2bf(a);
        nf[idx] = c; nf_bf[idx] = f2bf(c);
    }
}

// ca[row] = cur[row,:].w1 ; cb[row] = nbr[row,:].w2
__global__ __launch_bounds__(256) void rowdots_kernel(
    const float* __restrict__ cur, const float* __restrict__ nbr,
    const float* __restrict__ alignW,
    float* __restrict__ ca, float* __restrict__ cb)
{
    int row = blockIdx.x * 4 + (threadIdx.x >> 6);
    int lane = threadIdx.x & 63;
    const float* c = cur + (size_t)row * 256;
    const float* n = nbr + (size_t)row * 256;
    float p1 = 0.f, p2 = 0.f;
#pragma unroll
    for (int i = 0; i < 4; ++i) {
        int idx = lane + 64 * i;
        p1 = fmaf(c[idx], alignW[idx], p1);
        p2 = fmaf(n[idx], alignW[256 + idx], p2);
    }
#pragma unroll
    for (int off = 32; off > 0; off >>= 1) {
        p1 += __shfl_down(p1, off);
        p2 += __shfl_down(p2, off);
    }
    if (lane == 0) { ca[row] = p1; cb[row] = p2; }
}

// per (b,s): softmax over K=21 neighbors, context = elu(sum w_k * act_t[b,j_k,:]) -> bf16
__global__ __launch_bounds__(256) void attn_kernel(
    const int* __restrict__ deg, const float* __restrict__ ca,
    const float* __restrict__ cbrow, const float* __restrict__ act_t,
    const float* __restrict__ alignB, int d,
    ushort* __restrict__ context_bf, int S)
{
    const int KNB = 21;
    int bs = blockIdx.x;
    int b = bs >> 9;
    int tid = threadIdx.x;
    __shared__ float ss[KNB];
    __shared__ float se[KNB];
    __shared__ int sj[KNB];
    if (tid < KNB) {
        int j = deg[bs * KNB + tid];
        float cbv = (j >= 0) ? cbrow[b * S + j] : 0.f;
        float sc = ca[bs] + cbv + alignB[d];
        sc = sc > 0.f ? sc : 0.01f * sc;
        if (j < 0) sc += NEGC;
        sj[tid] = j;
        ss[tid] = sc;
    }
    __syncthreads();
    float mx = -3.4e38f;
#pragma unroll
    for (int k = 0; k < KNB; ++k) mx = fmaxf(mx, ss[k]);
    __syncthreads();
    if (tid < KNB) se[tid] = expf(ss[tid] - mx);
    __syncthreads();
    float sum = 0.f;
#pragma unroll
    for (int k = 0; k < KNB; ++k) sum += se[k];
    float inv = 1.f / sum;
    float acc = 0.f;
#pragma unroll
    for (int k = 0; k < KNB; ++k) {
        int j = sj[k];
        if (j >= 0)
            acc = fmaf(se[k], act_t[((size_t)b * S + j) * 256 + tid], acc);
    }
    acc *= inv;
    float o = acc > 0.f ? acc : expm1f(acc);
    context_bf[(size_t)bs * 256 + tid] = f2bf(o);
}

__global__ __launch_bounds__(256) void gru_gate_kernel(
    const ushort* __restrict__ gi, const ushort* __restrict__ gh,
    float* __restrict__ h, float* __restrict__ act,
    ushort* __restrict__ h_bf, ushort* __restrict__ act_bf)
{
    size_t row = blockIdx.x;
    int e = threadIdx.x;
    const ushort* gir = gi + row * 768;
    const ushort* ghr = gh + row * 768;
    float r = 1.f / (1.f + expf(-(bf2f(gir[e]) + bf2f(ghr[e]))));
    float z = 1.f / (1.f + expf(-(bf2f(gir[e + 256]) + bf2f(ghr[e + 256]))));
    float n = tanhf(bf2f(gir[e + 512]) + r * bf2f(ghr[e + 512]));
    size_t idx = row * 256 + e;
    float hv = h[idx];
    float hn = (1.f - z) * n + z * hv;
    h[idx] = hn;
    h_bf[idx] = f2bf(hn);
    float a = fmaxf(hn, 0.f);
    act[idx] = a;
    act_bf[idx] = f2bf(a);
}

__global__ __launch_bounds__(256) void seqpool_kernel(
    const float* __restrict__ act, const float* __restrict__ mask,
    const float* __restrict__ saW, float* __restrict__ seqfeat,
    float* __restrict__ actmol, float* __restrict__ moldot, int S)
{
    int b = blockIdx.x, tid = threadIdx.x;
    int lane = tid & 63, wv = tid >> 6;
    __shared__ float red[4];
    const float* ab = act + (size_t)b * S * 256;
    const float* mb = mask + b * S;
    float acc = 0.f;
    for (int s = 0; s < S; ++s)
        acc = fmaf(ab[(size_t)s * 256 + tid], mb[s], acc);
    seqfeat[b * 256 + tid] = acc;
    float am = fmaxf(acc, 0.f);
    actmol[b * 256 + tid] = am;
    float p = am * saW[tid];
#pragma unroll
    for (int off = 32; off > 0; off >>= 1) p += __shfl_down(p, off);
    if (lane == 0) red[wv] = p;
    __syncthreads();
    if (tid == 0) moldot[b] = red[0] + red[1] + red[2] + red[3];
}

__global__ __launch_bounds__(256) void seqscore_kernel(
    const float* __restrict__ act, const float* __restrict__ saW,
    const float* __restrict__ sab, const float* __restrict__ moldot,
    const float* __restrict__ mask, float* __restrict__ score, int S)
{
    int row = blockIdx.x * 4 + (threadIdx.x >> 6);
    int lane = threadIdx.x & 63;
    int b = row / S;
    const float* a = act + (size_t)row * 256;
    float p = 0.f;
#pragma unroll
    for (int i = 0; i < 4; ++i) {
        int idx = lane + 64 * i;
        p = fmaf(a[idx], saW[256 + idx], p);
    }
#pragma unroll
    for (int off = 32; off > 0; off >>= 1) p += __shfl_down(p, off);
    if (lane == 0) {
        float sc = moldot[b] + p + sab[0];
        sc = sc > 0.f ? sc : 0.01f * sc;
        if (mask[row] == 0.f) sc += NEGC;
        score[row] = sc;
    }
}

__global__ __launch_bounds__(256) void seqctx_kernel(
    const float* __restrict__ score, const float* __restrict__ mask,
    const float* __restrict__ feat, float* __restrict__ seqctx, int S)
{
    int b = blockIdx.x;
    int tid = threadIdx.x;
    int lane = tid & 63, wv = tid >> 6;
    __shared__ float sw[512];
    __shared__ float r1[4], r2[4];
    float lm = -3.4e38f;
    for (int s = tid; s < S; s += 256) {
        float v = score[b * S + s];
        sw[s] = v;
        lm = fmaxf(lm, v);
    }
#pragma unroll
    for (int off = 32; off > 0; off >>= 1) lm = fmaxf(lm, __shfl_down(lm, off));
    if (lane == 0) r1[wv] = lm;
    __syncthreads();
    float mx = fmaxf(fmaxf(r1[0], r1[1]), fmaxf(r1[2], r1[3]));
    float ls = 0.f;
    for (int s = tid; s < S; s += 256) {
        float e = expf(sw[s] - mx);
        sw[s] = e * mask[b * S + s];
        ls += e;
    }
#pragma unroll
    for (int off = 32; off > 0; off >>= 1) ls += __shfl_down(ls, off);
    if (lane == 0) r2[wv] = ls;
    __syncthreads();
    float inv = 1.f / (r2[0] + r2[1] + r2[2] + r2[3]);
    float acc = 0.f;
    for (int s = 0; s < S; ++s)
        acc = fmaf(sw[s], feat[((size_t)b * S + s) * 256 + tid], acc);
    acc *= inv;
    seqctx[b * 256 + tid] = acc > 0.f ? acc : expm1f(acc);
}

__global__ __launch_bounds__(256) void sgru_mm_kernel(
    const float* __restrict__ x, const float* __restrict__ hseq,
    const float* __restrict__ wih, const float* __restrict__ whh,
    const float* __restrict__ bih, const float* __restrict__ bhh,
    float* __restrict__ g)
{
    int out = blockIdx.x * 4 + (threadIdx.x >> 6);
    int lane = threadIdx.x & 63;
    int b = out / 1536;
    int j = out - b * 1536;
    const float* src; const float* w; const float* bp; int jj;
    if (j < 768) { src = x + b * 256; w = wih; bp = bih; jj = j; }
    else         { src = hseq + b * 256; w = whh; bp = bhh; jj = j - 768; }
    float p = 0.f;
#pragma unroll
    for (int i = 0; i < 4; ++i) {
        int idx = lane + 64 * i;
        p = fmaf(src[idx], w[(size_t)jj * 256 + idx], p);
    }
#pragma unroll
    for (int off = 32; off > 0; off >>= 1) p += __shfl_down(p, off);
    if (lane == 0) g[out] = p + bp[jj];
}

__global__ __launch_bounds__(256) void sgru_gate_kernel(
    const float* __restrict__ g, float* __restrict__ hseq, float* __restrict__ out)
{
    int b = blockIdx.x, e = threadIdx.x;
    const float* gr = g + b * 1536;
    float r = 1.f / (1.f + expf(-(gr[e] + gr[768 + e])));
    float z = 1.f / (1.f + expf(-(gr[256 + e] + gr[1024 + e])));
    float n = tanhf(gr[512 + e] + r * gr[1280 + e]);
    float hv = hseq[b * 256 + e];
    float hn = (1.f - z) * n + z * hv;
    hseq[b * 256 + e] = hn;
    out[b * 256 + e] = fmaxf(hn, 0.f);
}

extern "C" void kernel_launch(void* const* d_in, const int* in_sizes, int n_in,
                              void* d_out, int out_size, void* d_ws, size_t ws_size,
                              hipStream_t stream)
{
    const float* amino   = (const float*)d_in[0];
    const int*   deg     = (const int*)  d_in[1];
    const float* mask    = (const float*)d_in[2];
    const float* embW    = (const float*)d_in[3];
    const float* embB    = (const float*)d_in[4];
    const float* neighW  = (const float*)d_in[5];
    const float* neighB  = (const float*)d_in[6];
    const float* alignW  = (const float*)d_in[7];
    const float* alignB  = (const float*)d_in[8];
    const float* attendW = (const float*)d_in[9];
    const float* attendB = (const float*)d_in[10];
    const float* gruWih  = (const float*)d_in[11];
    const float* gruWhh  = (const float*)d_in[12];
    const float* gruBih  = (const float*)d_in[13];
    const float* gruBhh  = (const float*)d_in[14];
    const float* saW     = (const float*)d_in[15];
    const float* saB     = (const float*)d_in[16];
    const float* seqAttW = (const float*)d_in[17];
    const float* seqAttB = (const float*)d_in[18];
    const float* sWih    = (const float*)d_in[19];
    const float* sWhh    = (const float*)d_in[20];
    const float* sBih    = (const float*)d_in[21];
    const float* sBhh    = (const float*)d_in[22];
    float* out = (float*)d_out;

    const int B = 32, S = 512;
    const int BS = B * S;                 // 16384
    const size_t N1 = (size_t)BS * 256;   // 4194304

    // fp32 region
    float* ws   = (float*)d_ws;
    float* h    = ws;                 // N1
    float* act  = h + N1;             // N1
    float* attb = act + N1;           // N1 (act_t / feat_t)
    float* nf   = attb + N1;          // N1 (neighbor_feature fp32, round 0 rowdots)
    // bf16 region
    ushort* h_bf   = (ushort*)(nf + N1);
    ushort* act_bf = h_bf + N1;
    ushort* nb_bf  = act_bf + N1;          // nf_bf (round 0) then context_bf each round
    ushort* gi_bf  = nb_bf + N1;           // BS*768
    ushort* gh_bf  = gi_bf + (size_t)BS * 768;
    ushort* attW_bf = gh_bf + (size_t)BS * 768;   // 3*256*256
    ushort* wih_bf  = attW_bf + 3 * 256 * 256;    // 3*768*256
    ushort* whh_bf  = wih_bf + 3 * 768 * 256;
    ushort* saW2_bf = whh_bf + 3 * 768 * 256;     // 256*256
    // small fp32 tail
    float* smalls = (float*)(saW2_bf + 256 * 256);
    float* ca   = smalls;            // BS
    float* cb   = ca + BS;           // BS
    float* scor = cb + BS;           // BS
    float* seqf = scor + BS;         // B*256
    float* amol = seqf + B * 256;    // B*256
    float* mdot = amol + B * 256;    // B (pad 1024)
    float* sctx = mdot + 1024;       // B*256
    float* g    = sctx + B * 256;    // B*1536

    // weight conversions (bf16)
    cvt_kernel<<<(3 * 256 * 256) / 1024, 256, 0, stream>>>(attendW, attW_bf, (3 * 256 * 256) / 4);
    cvt_kernel<<<(3 * 768 * 256) / 1024, 256, 0, stream>>>(gruWih, wih_bf, (3 * 768 * 256) / 4);
    cvt_kernel<<<(3 * 768 * 256) / 1024, 256, 0, stream>>>(gruWhh, whh_bf, (3 * 768 * 256) / 4);
    cvt_kernel<<<(256 * 256) / 1024, 256, 0, stream>>>(seqAttW, saW2_bf, (256 * 256) / 4);

    embed_kernel<<<BS / 16, 256, 0, stream>>>(amino, embW, embB, neighW, neighB,
                                              h, nf, h_bf, nb_bf);

    for (int d = 0; d < 3; ++d) {
        const float*  cur_f  = (d == 0) ? h : act;
        const float*  nbr_f  = (d == 0) ? nf : act;
        const ushort* nbr_bf = (d == 0) ? nb_bf : act_bf;
        rowdots_kernel<<<BS / 4, 256, 0, stream>>>(cur_f, nbr_f, alignW + d * 512, ca, cb);
        dim3 g1(BS / 128, 256 / 128);
        gemm_mfma_kernel<<<g1, 256, 0, stream>>>(nbr_bf, attW_bf + d * 256 * 256,
                                                 attendB + d * 256, attb, (ushort*)nullptr,
                                                 BS, 256, 256);
        attn_kernel<<<BS, 256, 0, stream>>>(deg, ca, cb, attb, alignB, d, nb_bf, S);
        dim3 g2(BS / 128, 768 / 128);
        gemm_mfma_kernel<<<g2, 256, 0, stream>>>(nb_bf, wih_bf + d * 768 * 256,
                                                 gruBih + d * 768, (float*)nullptr, gi_bf,
                                                 BS, 768, 256);
        gemm_mfma_kernel<<<g2, 256, 0, stream>>>(h_bf, whh_bf + d * 768 * 256,
                                                 gruBhh + d * 768, (float*)nullptr, gh_bf,
                                                 BS, 768, 256);
        gru_gate_kernel<<<BS, 256, 0, stream>>>(gi_bf, gh_bf, h, act, h_bf, act_bf);
    }

    seqpool_kernel<<<B, 256, 0, stream>>>(act, mask, saW, seqf, amol, mdot, S);
    seqscore_kernel<<<BS / 4, 256, 0, stream>>>(act, saW, saB, mdot, mask, scor, S);
    dim3 g3(BS / 128, 256 / 128);
    gemm_mfma_kernel<<<g3, 256, 0, stream>>>(act_bf, saW2_bf, seqAttB, attb, (ushort*)nullptr,
                                             BS, 256, 256);
    seqctx_kernel<<<B, 256, 0, stream>>>(scor, mask, attb, sctx, S);

    for (int t = 0; t < 2; ++t) {
        sgru_mm_kernel<<<B * 1536 / 4, 256, 0, stream>>>(sctx, seqf, sWih, sWhh, sBih, sBhh, g);
        sgru_gate_kernel<<<B, 256, 0, stream>>>(g, seqf, out);
    }
}

// Round 3
// 513.904 us; speedup vs baseline: 2.6716x; 1.2264x over previous
//
#include <hip/hip_runtime.h>
#include <hip/hip_bf16.h>
#include <math.h>

// ProGAT: B=32, S=512, K=21, F_in=26, E=256, R=3, T=2
// Round 2: two-stage tree for seqpool/seqctx (32-block serial loops were 1.4% occupancy,
// 127us each); fast transcendentals (__expf-based sigmoid/tanh/elu) in gate kernels.

#define NEGC (-9.0e8f)

typedef __attribute__((ext_vector_type(8))) short bf16x8;
typedef __attribute__((ext_vector_type(4))) float f32x4;

__device__ __forceinline__ ushort f2bf(float x) {
    union { float f; unsigned u; } v; v.f = x;
    unsigned r = v.u + 0x7FFF + ((v.u >> 16) & 1);
    return (ushort)(r >> 16);
}
__device__ __forceinline__ float bf2f(ushort u) {
    union { unsigned u; float f; } v; v.u = ((unsigned)u) << 16;
    return v.f;
}
__device__ __forceinline__ float sigm_fast(float x) {
    return 1.f / (1.f + __expf(-x));
}
__device__ __forceinline__ float tanh_fast(float x) {
    return 1.f - 2.f / (__expf(2.f * x) + 1.f);
}
__device__ __forceinline__ float elu_fast(float x) {
    return x > 0.f ? x : (__expf(x) - 1.f);
}

typedef const __attribute__((address_space(1))) void gvoid_t;
typedef __attribute__((address_space(3))) void lvoid_t;

__global__ __launch_bounds__(256) void cvt_kernel(const float* __restrict__ src,
                                                  ushort* __restrict__ dst, int n4)
{
    int i = blockIdx.x * 256 + threadIdx.x;
    if (i < n4) {
        float4 v = *reinterpret_cast<const float4*>(&src[i * 4]);
        ushort4 o;
        o.x = f2bf(v.x); o.y = f2bf(v.y); o.z = f2bf(v.z); o.w = f2bf(v.w);
        *reinterpret_cast<ushort4*>(&dst[i * 4]) = o;
    }
}

// ---------------- bf16 MFMA GEMM: C[M,N] = A[M,K] @ W[N,K]^T + bias ----------------
__global__ __launch_bounds__(256) void gemm_mfma_kernel(
    const ushort* __restrict__ A, const ushort* __restrict__ W,
    const float* __restrict__ bias, float* __restrict__ Cf,
    ushort* __restrict__ Cb, int M, int N, int K)
{
    __shared__ __align__(16) short As[128 * 32];
    __shared__ __align__(16) short Bs[128 * 32];
    int tid = threadIdx.x;
    int lane = tid & 63;
    int w = tid >> 6;
    int wr = w >> 1, wc = w & 1;
    int bm = blockIdx.x * 128;
    int bn = blockIdx.y * 128;

    f32x4 acc[4][4];
#pragma unroll
    for (int m = 0; m < 4; ++m)
#pragma unroll
        for (int n = 0; n < 4; ++n) acc[m][n] = (f32x4){0.f, 0.f, 0.f, 0.f};

    for (int k0 = 0; k0 < K; k0 += 32) {
#pragma unroll
        for (int i = 0; i < 2; ++i) {
            int e = w * 1024 + i * 512 + lane * 8;
            int r = e >> 5, c = e & 31;
            const ushort* ga = A + (size_t)(bm + r) * K + (k0 + c);
            const ushort* gw = W + (size_t)(bn + r) * K + (k0 + c);
            __builtin_amdgcn_global_load_lds((gvoid_t*)ga, (lvoid_t*)&As[w * 1024 + i * 512], 16, 0, 0);
            __builtin_amdgcn_global_load_lds((gvoid_t*)gw, (lvoid_t*)&Bs[w * 1024 + i * 512], 16, 0, 0);
        }
        __syncthreads();
        bf16x8 af[4], bw[4];
        int ra = wr * 64 + (lane & 15);
        int rb = wc * 64 + (lane & 15);
        int kc = (lane >> 4) * 8;
#pragma unroll
        for (int m = 0; m < 4; ++m)
            af[m] = *reinterpret_cast<const bf16x8*>(&As[(ra + m * 16) * 32 + kc]);
#pragma unroll
        for (int n = 0; n < 4; ++n)
            bw[n] = *reinterpret_cast<const bf16x8*>(&Bs[(rb + n * 16) * 32 + kc]);
#pragma unroll
        for (int m = 0; m < 4; ++m)
#pragma unroll
            for (int n = 0; n < 4; ++n)
                acc[m][n] = __builtin_amdgcn_mfma_f32_16x16x32_bf16(af[m], bw[n], acc[m][n], 0, 0, 0);
        __syncthreads();
    }

    int cr0 = bm + wr * 64 + ((lane >> 4) * 4);
    int cc0 = bn + wc * 64 + (lane & 15);
#pragma unroll
    for (int n = 0; n < 4; ++n) {
        int col = cc0 + n * 16;
        float bv = bias[col];
#pragma unroll
        for (int m = 0; m < 4; ++m) {
            int row0 = cr0 + m * 16;
#pragma unroll
            for (int j = 0; j < 4; ++j) {
                float v = acc[m][n][j] + bv;
                size_t idx = (size_t)(row0 + j) * N + col;
                if (Cf) Cf[idx] = v;
                if (Cb) Cb[idx] = f2bf(v);
            }
        }
    }
}

// ---------------- embed ----------------
__global__ __launch_bounds__(256) void embed_kernel(
    const float* __restrict__ amino, const float* __restrict__ embW,
    const float* __restrict__ embB, const float* __restrict__ neighW,
    const float* __restrict__ neighB,
    float* __restrict__ h, float* __restrict__ nf,
    ushort* __restrict__ h_bf, ushort* __restrict__ nf_bf)
{
    const int FIN = 26;
    __shared__ float wE[26][256];
    __shared__ float wN[26][256];
    __shared__ float xs[16][26];
    int tid = threadIdx.x;
    for (int idx = tid; idx < FIN * 256; idx += 256) {
        int e = idx / FIN, f = idx - e * FIN;
        wE[f][e] = embW[idx];
        wN[f][e] = neighW[idx];
    }
    int row0 = blockIdx.x * 16;
    for (int idx = tid; idx < 16 * FIN; idx += 256) {
        int r = idx / FIN, f = idx - r * FIN;
        xs[r][f] = amino[(size_t)(row0 + r) * FIN + f];
    }
    __syncthreads();
    float acc1[16], acc2[16];
    float b1 = embB[tid], b2 = neighB[tid];
#pragma unroll
    for (int r = 0; r < 16; ++r) { acc1[r] = b1; acc2[r] = b2; }
    for (int f = 0; f < FIN; ++f) {
        float we = wE[f][tid], wn = wN[f][tid];
#pragma unroll
        for (int r = 0; r < 16; ++r) {
            float x = xs[r][f];
            acc1[r] = fmaf(x, we, acc1[r]);
            acc2[r] = fmaf(x, wn, acc2[r]);
        }
    }
#pragma unroll
    for (int r = 0; r < 16; ++r) {
        float a = acc1[r]; a = a > 0.f ? a : 0.01f * a;
        float c = acc2[r]; c = c > 0.f ? c : 0.01f * c;
        size_t idx = (size_t)(row0 + r) * 256 + tid;
        h[idx] = a;  h_bf[idx] = f2bf(a);
        nf[idx] = c; nf_bf[idx] = f2bf(c);
    }
}

__global__ __launch_bounds__(256) void rowdots_kernel(
    const float* __restrict__ cur, const float* __restrict__ nbr,
    const float* __restrict__ alignW,
    float* __restrict__ ca, float* __restrict__ cb)
{
    int row = blockIdx.x * 4 + (threadIdx.x >> 6);
    int lane = threadIdx.x & 63;
    const float* c = cur + (size_t)row * 256;
    const float* n = nbr + (size_t)row * 256;
    float p1 = 0.f, p2 = 0.f;
#pragma unroll
    for (int i = 0; i < 4; ++i) {
        int idx = lane + 64 * i;
        p1 = fmaf(c[idx], alignW[idx], p1);
        p2 = fmaf(n[idx], alignW[256 + idx], p2);
    }
#pragma unroll
    for (int off = 32; off > 0; off >>= 1) {
        p1 += __shfl_down(p1, off);
        p2 += __shfl_down(p2, off);
    }
    if (lane == 0) { ca[row] = p1; cb[row] = p2; }
}

// per (b,s): softmax over K=21 neighbors, context = elu(sum w_k * act_t[b,j_k,:]) -> bf16
__global__ __launch_bounds__(256) void attn_kernel(
    const int* __restrict__ deg, const float* __restrict__ ca,
    const float* __restrict__ cbrow, const float* __restrict__ act_t,
    const float* __restrict__ alignB, int d,
    ushort* __restrict__ context_bf, int S)
{
    const int KNB = 21;
    int bs = blockIdx.x;
    int b = bs >> 9;
    int tid = threadIdx.x;
    __shared__ float ss[KNB];
    __shared__ float se[KNB];
    __shared__ int sj[KNB];
    if (tid < KNB) {
        int j = deg[bs * KNB + tid];
        float cbv = (j >= 0) ? cbrow[b * S + j] : 0.f;
        float sc = ca[bs] + cbv + alignB[d];
        sc = sc > 0.f ? sc : 0.01f * sc;
        if (j < 0) sc += NEGC;
        sj[tid] = j;
        ss[tid] = sc;
    }
    __syncthreads();
    float mx = -3.4e38f;
#pragma unroll
    for (int k = 0; k < KNB; ++k) mx = fmaxf(mx, ss[k]);
    __syncthreads();
    if (tid < KNB) se[tid] = __expf(ss[tid] - mx);
    __syncthreads();
    float sum = 0.f;
#pragma unroll
    for (int k = 0; k < KNB; ++k) sum += se[k];
    float inv = 1.f / sum;
    float acc = 0.f;
#pragma unroll
    for (int k = 0; k < KNB; ++k) {
        int j = sj[k];
        if (j >= 0)
            acc = fmaf(se[k], act_t[((size_t)b * S + j) * 256 + tid], acc);
    }
    acc *= inv;
    context_bf[(size_t)bs * 256 + tid] = f2bf(elu_fast(acc));
}

__global__ __launch_bounds__(256) void gru_gate_kernel(
    const ushort* __restrict__ gi, const ushort* __restrict__ gh,
    float* __restrict__ h, float* __restrict__ act,
    ushort* __restrict__ h_bf, ushort* __restrict__ act_bf)
{
    size_t row = blockIdx.x;
    int e = threadIdx.x;
    const ushort* gir = gi + row * 768;
    const ushort* ghr = gh + row * 768;
    float r = sigm_fast(bf2f(gir[e]) + bf2f(ghr[e]));
    float z = sigm_fast(bf2f(gir[e + 256]) + bf2f(ghr[e + 256]));
    float n = tanh_fast(bf2f(gir[e + 512]) + r * bf2f(ghr[e + 512]));
    size_t idx = row * 256 + e;
    float hv = h[idx];
    float hn = (1.f - z) * n + z * hv;
    h[idx] = hn;
    h_bf[idx] = f2bf(hn);
    float a = fmaxf(hn, 0.f);
    act[idx] = a;
    act_bf[idx] = f2bf(a);
}

// ---------- seqpool: two-stage ----------
// stage 1: partial[b*NC+c][e] = sum_{s in chunk c} act[b,s,e]*mask[b,s]
__global__ __launch_bounds__(256) void seqpool_partial_kernel(
    const float* __restrict__ act, const float* __restrict__ mask,
    float* __restrict__ partial, int S, int CH)
{
    int bc = blockIdx.x;
    int NC = S / CH;
    int b = bc / NC, c = bc - b * NC;
    int tid = threadIdx.x;
    int s0 = c * CH;
    const float* ab = act + ((size_t)b * S + s0) * 256;
    const float* mb = mask + b * S + s0;
    float acc = 0.f;
    for (int s = 0; s < CH; ++s)
        acc = fmaf(ab[(size_t)s * 256 + tid], mb[s], acc);
    partial[(size_t)bc * 256 + tid] = acc;
}
// stage 2: seqfeat/actmol/moldot per b
__global__ __launch_bounds__(256) void seqpool_combine_kernel(
    const float* __restrict__ partial, const float* __restrict__ saW,
    float* __restrict__ seqfeat, float* __restrict__ actmol,
    float* __restrict__ moldot, int NC)
{
    int b = blockIdx.x, tid = threadIdx.x;
    int lane = tid & 63, wv = tid >> 6;
    __shared__ float red[4];
    float acc = 0.f;
    for (int c = 0; c < NC; ++c)
        acc += partial[((size_t)b * NC + c) * 256 + tid];
    seqfeat[b * 256 + tid] = acc;
    float am = fmaxf(acc, 0.f);
    actmol[b * 256 + tid] = am;
    float p = am * saW[tid];
#pragma unroll
    for (int off = 32; off > 0; off >>= 1) p += __shfl_down(p, off);
    if (lane == 0) red[wv] = p;
    __syncthreads();
    if (tid == 0) moldot[b] = red[0] + red[1] + red[2] + red[3];
}

__global__ __launch_bounds__(256) void seqscore_kernel(
    const float* __restrict__ act, const float* __restrict__ saW,
    const float* __restrict__ sab, const float* __restrict__ moldot,
    const float* __restrict__ mask, float* __restrict__ score, int S)
{
    int row = blockIdx.x * 4 + (threadIdx.x >> 6);
    int lane = threadIdx.x & 63;
    int b = row / S;
    const float* a = act + (size_t)row * 256;
    float p = 0.f;
#pragma unroll
    for (int i = 0; i < 4; ++i) {
        int idx = lane + 64 * i;
        p = fmaf(a[idx], saW[256 + idx], p);
    }
#pragma unroll
    for (int off = 32; off > 0; off >>= 1) p += __shfl_down(p, off);
    if (lane == 0) {
        float sc = moldot[b] + p + sab[0];
        sc = sc > 0.f ? sc : 0.01f * sc;
        if (mask[row] == 0.f) sc += NEGC;
        score[row] = sc;
    }
}

// softmax over S per b -> weights w[b,s] = exp(sc-mx)*mask/sum
__global__ __launch_bounds__(256) void seqsm_kernel(
    const float* __restrict__ score, const float* __restrict__ mask,
    float* __restrict__ wout, int S)
{
    int b = blockIdx.x;
    int tid = threadIdx.x;
    int lane = tid & 63, wv = tid >> 6;
    __shared__ float sw[512];
    __shared__ float r1[4], r2[4];
    float lm = -3.4e38f;
    for (int s = tid; s < S; s += 256) {
        float v = score[b * S + s];
        sw[s] = v;
        lm = fmaxf(lm, v);
    }
#pragma unroll
    for (int off = 32; off > 0; off >>= 1) lm = fmaxf(lm, __shfl_down(lm, off));
    if (lane == 0) r1[wv] = lm;
    __syncthreads();
    float mx = fmaxf(fmaxf(r1[0], r1[1]), fmaxf(r1[2], r1[3]));
    float ls = 0.f;
    for (int s = tid; s < S; s += 256) {
        float e = __expf(sw[s] - mx);
        sw[s] = e * mask[b * S + s];
        ls += e;
    }
#pragma unroll
    for (int off = 32; off > 0; off >>= 1) ls += __shfl_down(ls, off);
    if (lane == 0) r2[wv] = ls;
    __syncthreads();
    float inv = 1.f / (r2[0] + r2[1] + r2[2] + r2[3]);
    for (int s = tid; s < S; s += 256)
        wout[b * S + s] = sw[s] * inv;
}

// partial weighted sum over s-chunk
__global__ __launch_bounds__(256) void seqctx_partial_kernel(
    const float* __restrict__ w, const float* __restrict__ feat,
    float* __restrict__ partial, int S, int CH)
{
    int bc = blockIdx.x;
    int NC = S / CH;
    int b = bc / NC, c = bc - b * NC;
    int tid = threadIdx.x;
    int s0 = c * CH;
    const float* fb = feat + ((size_t)b * S + s0) * 256;
    const float* wb = w + b * S + s0;
    float acc = 0.f;
    for (int s = 0; s < CH; ++s)
        acc = fmaf(wb[s], fb[(size_t)s * 256 + tid], acc);
    partial[(size_t)bc * 256 + tid] = acc;
}

__global__ __launch_bounds__(256) void seqctx_combine_kernel(
    const float* __restrict__ partial, float* __restrict__ sctx, int NC)
{
    int b = blockIdx.x, tid = threadIdx.x;
    float acc = 0.f;
    for (int c = 0; c < NC; ++c)
        acc += partial[((size_t)b * NC + c) * 256 + tid];
    sctx[b * 256 + tid] = elu_fast(acc);
}

__global__ __launch_bounds__(256) void sgru_mm_kernel(
    const float* __restrict__ x, const float* __restrict__ hseq,
    const float* __restrict__ wih, const float* __restrict__ whh,
    const float* __restrict__ bih, const float* __restrict__ bhh,
    float* __restrict__ g)
{
    int out = blockIdx.x * 4 + (threadIdx.x >> 6);
    int lane = threadIdx.x & 63;
    int b = out / 1536;
    int j = out - b * 1536;
    const float* src; const float* w; const float* bp; int jj;
    if (j < 768) { src = x + b * 256; w = wih; bp = bih; jj = j; }
    else         { src = hseq + b * 256; w = whh; bp = bhh; jj = j - 768; }
    float p = 0.f;
#pragma unroll
    for (int i = 0; i < 4; ++i) {
        int idx = lane + 64 * i;
        p = fmaf(src[idx], w[(size_t)jj * 256 + idx], p);
    }
#pragma unroll
    for (int off = 32; off > 0; off >>= 1) p += __shfl_down(p, off);
    if (lane == 0) g[out] = p + bp[jj];
}

__global__ __launch_bounds__(256) void sgru_gate_kernel(
    const float* __restrict__ g, float* __restrict__ hseq, float* __restrict__ out)
{
    int b = blockIdx.x, e = threadIdx.x;
    const float* gr = g + b * 1536;
    float r = sigm_fast(gr[e] + gr[768 + e]);
    float z = sigm_fast(gr[256 + e] + gr[1024 + e]);
    float n = tanh_fast(gr[512 + e] + r * gr[1280 + e]);
    float hv = hseq[b * 256 + e];
    float hn = (1.f - z) * n + z * hv;
    hseq[b * 256 + e] = hn;
    out[b * 256 + e] = fmaxf(hn, 0.f);
}

extern "C" void kernel_launch(void* const* d_in, const int* in_sizes, int n_in,
                              void* d_out, int out_size, void* d_ws, size_t ws_size,
                              hipStream_t stream)
{
    const float* amino   = (const float*)d_in[0];
    const int*   deg     = (const int*)  d_in[1];
    const float* mask    = (const float*)d_in[2];
    const float* embW    = (const float*)d_in[3];
    const float* embB    = (const float*)d_in[4];
    const float* neighW  = (const float*)d_in[5];
    const float* neighB  = (const float*)d_in[6];
    const float* alignW  = (const float*)d_in[7];
    const float* alignB  = (const float*)d_in[8];
    const float* attendW = (const float*)d_in[9];
    const float* attendB = (const float*)d_in[10];
    const float* gruWih  = (const float*)d_in[11];
    const float* gruWhh  = (const float*)d_in[12];
    const float* gruBih  = (const float*)d_in[13];
    const float* gruBhh  = (const float*)d_in[14];
    const float* saW     = (const float*)d_in[15];
    const float* saB     = (const float*)d_in[16];
    const float* seqAttW = (const float*)d_in[17];
    const float* seqAttB = (const float*)d_in[18];
    const float* sWih    = (const float*)d_in[19];
    const float* sWhh    = (const float*)d_in[20];
    const float* sBih    = (const float*)d_in[21];
    const float* sBhh    = (const float*)d_in[22];
    float* out = (float*)d_out;

    const int B = 32, S = 512;
    const int BS = B * S;                 // 16384
    const size_t N1 = (size_t)BS * 256;   // 4194304
    const int CH = 32, NC = S / CH;       // 16 chunks

    float* ws   = (float*)d_ws;
    float* h    = ws;                 // N1
    float* act  = h + N1;             // N1
    float* attb = act + N1;           // N1 (act_t / feat_t)
    float* nf   = attb + N1;          // N1
    ushort* h_bf   = (ushort*)(nf + N1);
    ushort* act_bf = h_bf + N1;
    ushort* nb_bf  = act_bf + N1;
    ushort* gi_bf  = nb_bf + N1;
    ushort* gh_bf  = gi_bf + (size_t)BS * 768;
    ushort* attW_bf = gh_bf + (size_t)BS * 768;
    ushort* wih_bf  = attW_bf + 3 * 256 * 256;
    ushort* whh_bf  = wih_bf + 3 * 768 * 256;
    ushort* saW2_bf = whh_bf + 3 * 768 * 256;
    float* smalls = (float*)(saW2_bf + 256 * 256);
    float* ca   = smalls;            // BS
    float* cb   = ca + BS;           // BS
    float* scor = cb + BS;           // BS
    float* wbuf = scor + BS;         // BS
    float* seqf = wbuf + BS;         // B*256
    float* amol = seqf + B * 256;    // B*256
    float* mdot = amol + B * 256;    // B (pad 1024)
    float* sctx = mdot + 1024;       // B*256
    float* g    = sctx + B * 256;    // B*1536
    float* part = g + B * 1536;      // B*NC*256 = 131072

    cvt_kernel<<<(3 * 256 * 256) / 1024, 256, 0, stream>>>(attendW, attW_bf, (3 * 256 * 256) / 4);
    cvt_kernel<<<(3 * 768 * 256) / 1024, 256, 0, stream>>>(gruWih, wih_bf, (3 * 768 * 256) / 4);
    cvt_kernel<<<(3 * 768 * 256) / 1024, 256, 0, stream>>>(gruWhh, whh_bf, (3 * 768 * 256) / 4);
    cvt_kernel<<<(256 * 256) / 1024, 256, 0, stream>>>(seqAttW, saW2_bf, (256 * 256) / 4);

    embed_kernel<<<BS / 16, 256, 0, stream>>>(amino, embW, embB, neighW, neighB,
                                              h, nf, h_bf, nb_bf);

    for (int d = 0; d < 3; ++d) {
        const float*  cur_f  = (d == 0) ? h : act;
        const float*  nbr_f  = (d == 0) ? nf : act;
        const ushort* nbr_bf = (d == 0) ? nb_bf : act_bf;
        rowdots_kernel<<<BS / 4, 256, 0, stream>>>(cur_f, nbr_f, alignW + d * 512, ca, cb);
        dim3 g1(BS / 128, 256 / 128);
        gemm_mfma_kernel<<<g1, 256, 0, stream>>>(nbr_bf, attW_bf + d * 256 * 256,
                                                 attendB + d * 256, attb, (ushort*)nullptr,
                                                 BS, 256, 256);
        attn_kernel<<<BS, 256, 0, stream>>>(deg, ca, cb, attb, alignB, d, nb_bf, S);
        dim3 g2(BS / 128, 768 / 128);
        gemm_mfma_kernel<<<g2, 256, 0, stream>>>(nb_bf, wih_bf + d * 768 * 256,
                                                 gruBih + d * 768, (float*)nullptr, gi_bf,
                                                 BS, 768, 256);
        gemm_mfma_kernel<<<g2, 256, 0, stream>>>(h_bf, whh_bf + d * 768 * 256,
                                                 gruBhh + d * 768, (float*)nullptr, gh_bf,
                                                 BS, 768, 256);
        gru_gate_kernel<<<BS, 256, 0, stream>>>(gi_bf, gh_bf, h, act, h_bf, act_bf);
    }

    seqpool_partial_kernel<<<B * NC, 256, 0, stream>>>(act, mask, part, S, CH);
    seqpool_combine_kernel<<<B, 256, 0, stream>>>(part, saW, seqf, amol, mdot, NC);
    seqscore_kernel<<<BS / 4, 256, 0, stream>>>(act, saW, saB, mdot, mask, scor, S);
    dim3 g3(BS / 128, 256 / 128);
    gemm_mfma_kernel<<<g3, 256, 0, stream>>>(act_bf, saW2_bf, seqAttB, attb, (ushort*)nullptr,
                                             BS, 256, 256);
    seqsm_kernel<<<B, 256, 0, stream>>>(scor, mask, wbuf, S);
    seqctx_partial_kernel<<<B * NC, 256, 0, stream>>>(wbuf, attb, part, S, CH);
    seqctx_combine_kernel<<<B, 256, 0, stream>>>(part, sctx, NC);

    for (int t = 0; t < 2; ++t) {
        sgru_mm_kernel<<<B * 1536 / 4, 256, 0, stream>>>(sctx, seqf, sWih, sWhh, sBih, sBhh, g);
        sgru_gate_kernel<<<B, 256, 0, stream>>>(g, seqf, out);
    }
}

// Round 4
// 401.855 us; speedup vs baseline: 3.4165x; 1.2788x over previous
//
#include <hip/hip_runtime.h>
#include <hip/hip_bf16.h>
#include <math.h>

// ProGAT: B=32, S=512, K=21, F_in=26, E=256, R=3, T=2
// Round 3: attn gather over bf16 act_t (fp32 attb eliminated), 4 rows/block with
// wave-per-row gather (ushort4 = 8B/lane), XCD-clustered block swizzle so each XCD's
// L2 serves 4 b-slices (1 MB). feat_t also bf16-only.

#define NEGC (-9.0e8f)

typedef __attribute__((ext_vector_type(8))) short bf16x8;
typedef __attribute__((ext_vector_type(4))) float f32x4;

__device__ __forceinline__ ushort f2bf(float x) {
    union { float f; unsigned u; } v; v.f = x;
    unsigned r = v.u + 0x7FFF + ((v.u >> 16) & 1);
    return (ushort)(r >> 16);
}
__device__ __forceinline__ float bf2f(ushort u) {
    union { unsigned u; float f; } v; v.u = ((unsigned)u) << 16;
    return v.f;
}
__device__ __forceinline__ float sigm_fast(float x) {
    return 1.f / (1.f + __expf(-x));
}
__device__ __forceinline__ float tanh_fast(float x) {
    return 1.f - 2.f / (__expf(2.f * x) + 1.f);
}
__device__ __forceinline__ float elu_fast(float x) {
    return x > 0.f ? x : (__expf(x) - 1.f);
}

typedef const __attribute__((address_space(1))) void gvoid_t;
typedef __attribute__((address_space(3))) void lvoid_t;

__global__ __launch_bounds__(256) void cvt_kernel(const float* __restrict__ src,
                                                  ushort* __restrict__ dst, int n4)
{
    int i = blockIdx.x * 256 + threadIdx.x;
    if (i < n4) {
        float4 v = *reinterpret_cast<const float4*>(&src[i * 4]);
        ushort4 o;
        o.x = f2bf(v.x); o.y = f2bf(v.y); o.z = f2bf(v.z); o.w = f2bf(v.w);
        *reinterpret_cast<ushort4*>(&dst[i * 4]) = o;
    }
}

// ---------------- bf16 MFMA GEMM: C[M,N] = A[M,K] @ W[N,K]^T + bias ----------------
__global__ __launch_bounds__(256) void gemm_mfma_kernel(
    const ushort* __restrict__ A, const ushort* __restrict__ W,
    const float* __restrict__ bias, float* __restrict__ Cf,
    ushort* __restrict__ Cb, int M, int N, int K)
{
    __shared__ __align__(16) short As[128 * 32];
    __shared__ __align__(16) short Bs[128 * 32];
    int tid = threadIdx.x;
    int lane = tid & 63;
    int w = tid >> 6;
    int wr = w >> 1, wc = w & 1;
    int bm = blockIdx.x * 128;
    int bn = blockIdx.y * 128;

    f32x4 acc[4][4];
#pragma unroll
    for (int m = 0; m < 4; ++m)
#pragma unroll
        for (int n = 0; n < 4; ++n) acc[m][n] = (f32x4){0.f, 0.f, 0.f, 0.f};

    for (int k0 = 0; k0 < K; k0 += 32) {
#pragma unroll
        for (int i = 0; i < 2; ++i) {
            int e = w * 1024 + i * 512 + lane * 8;
            int r = e >> 5, c = e & 31;
            const ushort* ga = A + (size_t)(bm + r) * K + (k0 + c);
            const ushort* gw = W + (size_t)(bn + r) * K + (k0 + c);
            __builtin_amdgcn_global_load_lds((gvoid_t*)ga, (lvoid_t*)&As[w * 1024 + i * 512], 16, 0, 0);
            __builtin_amdgcn_global_load_lds((gvoid_t*)gw, (lvoid_t*)&Bs[w * 1024 + i * 512], 16, 0, 0);
        }
        __syncthreads();
        bf16x8 af[4], bw[4];
        int ra = wr * 64 + (lane & 15);
        int rb = wc * 64 + (lane & 15);
        int kc = (lane >> 4) * 8;
#pragma unroll
        for (int m = 0; m < 4; ++m)
            af[m] = *reinterpret_cast<const bf16x8*>(&As[(ra + m * 16) * 32 + kc]);
#pragma unroll
        for (int n = 0; n < 4; ++n)
            bw[n] = *reinterpret_cast<const bf16x8*>(&Bs[(rb + n * 16) * 32 + kc]);
#pragma unroll
        for (int m = 0; m < 4; ++m)
#pragma unroll
            for (int n = 0; n < 4; ++n)
                acc[m][n] = __builtin_amdgcn_mfma_f32_16x16x32_bf16(af[m], bw[n], acc[m][n], 0, 0, 0);
        __syncthreads();
    }

    int cr0 = bm + wr * 64 + ((lane >> 4) * 4);
    int cc0 = bn + wc * 64 + (lane & 15);
#pragma unroll
    for (int n = 0; n < 4; ++n) {
        int col = cc0 + n * 16;
        float bv = bias[col];
#pragma unroll
        for (int m = 0; m < 4; ++m) {
            int row0 = cr0 + m * 16;
#pragma unroll
            for (int j = 0; j < 4; ++j) {
                float v = acc[m][n][j] + bv;
                size_t idx = (size_t)(row0 + j) * N + col;
                if (Cf) Cf[idx] = v;
                if (Cb) Cb[idx] = f2bf(v);
            }
        }
    }
}

// ---------------- embed ----------------
__global__ __launch_bounds__(256) void embed_kernel(
    const float* __restrict__ amino, const float* __restrict__ embW,
    const float* __restrict__ embB, const float* __restrict__ neighW,
    const float* __restrict__ neighB,
    float* __restrict__ h, float* __restrict__ nf,
    ushort* __restrict__ h_bf, ushort* __restrict__ nf_bf)
{
    const int FIN = 26;
    __shared__ float wE[26][256];
    __shared__ float wN[26][256];
    __shared__ float xs[16][26];
    int tid = threadIdx.x;
    for (int idx = tid; idx < FIN * 256; idx += 256) {
        int e = idx / FIN, f = idx - e * FIN;
        wE[f][e] = embW[idx];
        wN[f][e] = neighW[idx];
    }
    int row0 = blockIdx.x * 16;
    for (int idx = tid; idx < 16 * FIN; idx += 256) {
        int r = idx / FIN, f = idx - r * FIN;
        xs[r][f] = amino[(size_t)(row0 + r) * FIN + f];
    }
    __syncthreads();
    float acc1[16], acc2[16];
    float b1 = embB[tid], b2 = neighB[tid];
#pragma unroll
    for (int r = 0; r < 16; ++r) { acc1[r] = b1; acc2[r] = b2; }
    for (int f = 0; f < FIN; ++f) {
        float we = wE[f][tid], wn = wN[f][tid];
#pragma unroll
        for (int r = 0; r < 16; ++r) {
            float x = xs[r][f];
            acc1[r] = fmaf(x, we, acc1[r]);
            acc2[r] = fmaf(x, wn, acc2[r]);
        }
    }
#pragma unroll
    for (int r = 0; r < 16; ++r) {
        float a = acc1[r]; a = a > 0.f ? a : 0.01f * a;
        float c = acc2[r]; c = c > 0.f ? c : 0.01f * c;
        size_t idx = (size_t)(row0 + r) * 256 + tid;
        h[idx] = a;  h_bf[idx] = f2bf(a);
        nf[idx] = c; nf_bf[idx] = f2bf(c);
    }
}

__global__ __launch_bounds__(256) void rowdots_kernel(
    const float* __restrict__ cur, const float* __restrict__ nbr,
    const float* __restrict__ alignW,
    float* __restrict__ ca, float* __restrict__ cb)
{
    int row = blockIdx.x * 4 + (threadIdx.x >> 6);
    int lane = threadIdx.x & 63;
    const float* c = cur + (size_t)row * 256;
    const float* n = nbr + (size_t)row * 256;
    float p1 = 0.f, p2 = 0.f;
#pragma unroll
    for (int i = 0; i < 4; ++i) {
        int idx = lane + 64 * i;
        p1 = fmaf(c[idx], alignW[idx], p1);
        p2 = fmaf(n[idx], alignW[256 + idx], p2);
    }
#pragma unroll
    for (int off = 32; off > 0; off >>= 1) {
        p1 += __shfl_down(p1, off);
        p2 += __shfl_down(p2, off);
    }
    if (lane == 0) { ca[row] = p1; cb[row] = p2; }
}

// attn: 4 rows/block, one wave per row. Gather bf16 act_t rows with ushort4/lane.
// Grid 4096 blocks, XCD-swizzled so each XCD handles 4 consecutive b's (L2-resident 1MB).
__global__ __launch_bounds__(256) void attn_kernel(
    const int* __restrict__ deg, const float* __restrict__ ca,
    const float* __restrict__ cbrow, const ushort* __restrict__ act_t,
    const float* __restrict__ alignB, int d,
    ushort* __restrict__ context_bf, int S)
{
    const int KNB = 21;
    // bijective swizzle: 4096 blocks, 8 XCDs, 512 contiguous per XCD
    int raw = blockIdx.x;
    int bid = (raw & 7) * 512 + (raw >> 3);
    int bs0 = bid * 4;
    int b = bs0 >> 9;
    int tid = threadIdx.x;
    int wv = tid >> 6, lane = tid & 63;
    int bs = bs0 + wv;
    __shared__ float ss[4][KNB];
    __shared__ int   sj[4][KNB];
    if (lane < KNB) {
        int j = deg[bs * KNB + lane];
        float cbv = (j >= 0) ? cbrow[b * S + j] : 0.f;
        float sc = ca[bs] + cbv + alignB[d];
        sc = sc > 0.f ? sc : 0.01f * sc;
        if (j < 0) sc += NEGC;
        sj[wv][lane] = j;
        ss[wv][lane] = sc;
    }
    __syncthreads();
    float mx = -3.4e38f;
#pragma unroll
    for (int k = 0; k < KNB; ++k) mx = fmaxf(mx, ss[wv][k]);
    float se[KNB];
    float sum = 0.f;
#pragma unroll
    for (int k = 0; k < KNB; ++k) { se[k] = __expf(ss[wv][k] - mx); sum += se[k]; }
    float inv = 1.f / sum;
    const ushort* base = act_t + (size_t)b * S * 256 + lane * 4;
    float a0 = 0.f, a1 = 0.f, a2 = 0.f, a3 = 0.f;
#pragma unroll
    for (int k = 0; k < KNB; ++k) {
        int j = sj[wv][k];
        if (j >= 0) {
            ushort4 v = *reinterpret_cast<const ushort4*>(base + (size_t)j * 256);
            float wk = se[k];
            a0 = fmaf(wk, bf2f(v.x), a0);
            a1 = fmaf(wk, bf2f(v.y), a1);
            a2 = fmaf(wk, bf2f(v.z), a2);
            a3 = fmaf(wk, bf2f(v.w), a3);
        }
    }
    ushort4 o;
    o.x = f2bf(elu_fast(a0 * inv));
    o.y = f2bf(elu_fast(a1 * inv));
    o.z = f2bf(elu_fast(a2 * inv));
    o.w = f2bf(elu_fast(a3 * inv));
    *reinterpret_cast<ushort4*>(&context_bf[(size_t)bs * 256 + lane * 4]) = o;
}

__global__ __launch_bounds__(256) void gru_gate_kernel(
    const ushort* __restrict__ gi, const ushort* __restrict__ gh,
    float* __restrict__ h, float* __restrict__ act,
    ushort* __restrict__ h_bf, ushort* __restrict__ act_bf)
{
    size_t row = blockIdx.x;
    int e = threadIdx.x;
    const ushort* gir = gi + row * 768;
    const ushort* ghr = gh + row * 768;
    float r = sigm_fast(bf2f(gir[e]) + bf2f(ghr[e]));
    float z = sigm_fast(bf2f(gir[e + 256]) + bf2f(ghr[e + 256]));
    float n = tanh_fast(bf2f(gir[e + 512]) + r * bf2f(ghr[e + 512]));
    size_t idx = row * 256 + e;
    float hv = h[idx];
    float hn = (1.f - z) * n + z * hv;
    h[idx] = hn;
    h_bf[idx] = f2bf(hn);
    float a = fmaxf(hn, 0.f);
    act[idx] = a;
    act_bf[idx] = f2bf(a);
}

// ---------- seqpool: two-stage ----------
__global__ __launch_bounds__(256) void seqpool_partial_kernel(
    const float* __restrict__ act, const float* __restrict__ mask,
    float* __restrict__ partial, int S, int CH)
{
    int bc = blockIdx.x;
    int NC = S / CH;
    int b = bc / NC, c = bc - b * NC;
    int tid = threadIdx.x;
    int s0 = c * CH;
    const float* ab = act + ((size_t)b * S + s0) * 256;
    const float* mb = mask + b * S + s0;
    float acc = 0.f;
    for (int s = 0; s < CH; ++s)
        acc = fmaf(ab[(size_t)s * 256 + tid], mb[s], acc);
    partial[(size_t)bc * 256 + tid] = acc;
}
__global__ __launch_bounds__(256) void seqpool_combine_kernel(
    const float* __restrict__ partial, const float* __restrict__ saW,
    float* __restrict__ seqfeat, float* __restrict__ actmol,
    float* __restrict__ moldot, int NC)
{
    int b = blockIdx.x, tid = threadIdx.x;
    int lane = tid & 63, wv = tid >> 6;
    __shared__ float red[4];
    float acc = 0.f;
    for (int c = 0; c < NC; ++c)
        acc += partial[((size_t)b * NC + c) * 256 + tid];
    seqfeat[b * 256 + tid] = acc;
    float am = fmaxf(acc, 0.f);
    actmol[b * 256 + tid] = am;
    float p = am * saW[tid];
#pragma unroll
    for (int off = 32; off > 0; off >>= 1) p += __shfl_down(p, off);
    if (lane == 0) red[wv] = p;
    __syncthreads();
    if (tid == 0) moldot[b] = red[0] + red[1] + red[2] + red[3];
}

__global__ __launch_bounds__(256) void seqscore_kernel(
    const float* __restrict__ act, const float* __restrict__ saW,
    const float* __restrict__ sab, const float* __restrict__ moldot,
    const float* __restrict__ mask, float* __restrict__ score, int S)
{
    int row = blockIdx.x * 4 + (threadIdx.x >> 6);
    int lane = threadIdx.x & 63;
    int b = row / S;
    const float* a = act + (size_t)row * 256;
    float p = 0.f;
#pragma unroll
    for (int i = 0; i < 4; ++i) {
        int idx = lane + 64 * i;
        p = fmaf(a[idx], saW[256 + idx], p);
    }
#pragma unroll
    for (int off = 32; off > 0; off >>= 1) p += __shfl_down(p, off);
    if (lane == 0) {
        float sc = moldot[b] + p + sab[0];
        sc = sc > 0.f ? sc : 0.01f * sc;
        if (mask[row] == 0.f) sc += NEGC;
        score[row] = sc;
    }
}

__global__ __launch_bounds__(256) void seqsm_kernel(
    const float* __restrict__ score, const float* __restrict__ mask,
    float* __restrict__ wout, int S)
{
    int b = blockIdx.x;
    int tid = threadIdx.x;
    int lane = tid & 63, wv = tid >> 6;
    __shared__ float sw[512];
    __shared__ float r1[4], r2[4];
    float lm = -3.4e38f;
    for (int s = tid; s < S; s += 256) {
        float v = score[b * S + s];
        sw[s] = v;
        lm = fmaxf(lm, v);
    }
#pragma unroll
    for (int off = 32; off > 0; off >>= 1) lm = fmaxf(lm, __shfl_down(lm, off));
    if (lane == 0) r1[wv] = lm;
    __syncthreads();
    float mx = fmaxf(fmaxf(r1[0], r1[1]), fmaxf(r1[2], r1[3]));
    float ls = 0.f;
    for (int s = tid; s < S; s += 256) {
        float e = __expf(sw[s] - mx);
        sw[s] = e * mask[b * S + s];
        ls += e;
    }
#pragma unroll
    for (int off = 32; off > 0; off >>= 1) ls += __shfl_down(ls, off);
    if (lane == 0) r2[wv] = ls;
    __syncthreads();
    float inv = 1.f / (r2[0] + r2[1] + r2[2] + r2[3]);
    for (int s = tid; s < S; s += 256)
        wout[b * S + s] = sw[s] * inv;
}

// partial weighted sum over s-chunk (bf16 feat)
__global__ __launch_bounds__(256) void seqctx_partial_kernel(
    const float* __restrict__ w, const ushort* __restrict__ feat,
    float* __restrict__ partial, int S, int CH)
{
    int bc = blockIdx.x;
    int NC = S / CH;
    int b = bc / NC, c = bc - b * NC;
    int tid = threadIdx.x;
    int s0 = c * CH;
    const ushort* fb = feat + ((size_t)b * S + s0) * 256;
    const float* wb = w + b * S + s0;
    float acc = 0.f;
    for (int s = 0; s < CH; ++s)
        acc = fmaf(wb[s], bf2f(fb[(size_t)s * 256 + tid]), acc);
    partial[(size_t)bc * 256 + tid] = acc;
}

__global__ __launch_bounds__(256) void seqctx_combine_kernel(
    const float* __restrict__ partial, float* __restrict__ sctx, int NC)
{
    int b = blockIdx.x, tid = threadIdx.x;
    float acc = 0.f;
    for (int c = 0; c < NC; ++c)
        acc += partial[((size_t)b * NC + c) * 256 + tid];
    sctx[b * 256 + tid] = elu_fast(acc);
}

__global__ __launch_bounds__(256) void sgru_mm_kernel(
    const float* __restrict__ x, const float* __restrict__ hseq,
    const float* __restrict__ wih, const float* __restrict__ whh,
    const float* __restrict__ bih, const float* __restrict__ bhh,
    float* __restrict__ g)
{
    int out = blockIdx.x * 4 + (threadIdx.x >> 6);
    int lane = threadIdx.x & 63;
    int b = out / 1536;
    int j = out - b * 1536;
    const float* src; const float* w; const float* bp; int jj;
    if (j < 768) { src = x + b * 256; w = wih; bp = bih; jj = j; }
    else         { src = hseq + b * 256; w = whh; bp = bhh; jj = j - 768; }
    float p = 0.f;
#pragma unroll
    for (int i = 0; i < 4; ++i) {
        int idx = lane + 64 * i;
        p = fmaf(src[idx], w[(size_t)jj * 256 + idx], p);
    }
#pragma unroll
    for (int off = 32; off > 0; off >>= 1) p += __shfl_down(p, off);
    if (lane == 0) g[out] = p + bp[jj];
}

__global__ __launch_bounds__(256) void sgru_gate_kernel(
    const float* __restrict__ g, float* __restrict__ hseq, float* __restrict__ out)
{
    int b = blockIdx.x, e = threadIdx.x;
    const float* gr = g + b * 1536;
    float r = sigm_fast(gr[e] + gr[768 + e]);
    float z = sigm_fast(gr[256 + e] + gr[1024 + e]);
    float n = tanh_fast(gr[512 + e] + r * gr[1280 + e]);
    float hv = hseq[b * 256 + e];
    float hn = (1.f - z) * n + z * hv;
    hseq[b * 256 + e] = hn;
    out[b * 256 + e] = fmaxf(hn, 0.f);
}

extern "C" void kernel_launch(void* const* d_in, const int* in_sizes, int n_in,
                              void* d_out, int out_size, void* d_ws, size_t ws_size,
                              hipStream_t stream)
{
    const float* amino   = (const float*)d_in[0];
    const int*   deg     = (const int*)  d_in[1];
    const float* mask    = (const float*)d_in[2];
    const float* embW    = (const float*)d_in[3];
    const float* embB    = (const float*)d_in[4];
    const float* neighW  = (const float*)d_in[5];
    const float* neighB  = (const float*)d_in[6];
    const float* alignW  = (const float*)d_in[7];
    const float* alignB  = (const float*)d_in[8];
    const float* attendW = (const float*)d_in[9];
    const float* attendB = (const float*)d_in[10];
    const float* gruWih  = (const float*)d_in[11];
    const float* gruWhh  = (const float*)d_in[12];
    const float* gruBih  = (const float*)d_in[13];
    const float* gruBhh  = (const float*)d_in[14];
    const float* saW     = (const float*)d_in[15];
    const float* saB     = (const float*)d_in[16];
    const float* seqAttW = (const float*)d_in[17];
    const float* seqAttB = (const float*)d_in[18];
    const float* sWih    = (const float*)d_in[19];
    const float* sWhh    = (const float*)d_in[20];
    const float* sBih    = (const float*)d_in[21];
    const float* sBhh    = (const float*)d_in[22];
    float* out = (float*)d_out;

    const int B = 32, S = 512;
    const int BS = B * S;                 // 16384
    const size_t N1 = (size_t)BS * 256;   // 4194304
    const int CH = 32, NC = S / CH;       // 16 chunks

    float* ws   = (float*)d_ws;
    float* h    = ws;                 // N1 fp32
    float* act  = h + N1;             // N1 fp32
    float* nf   = act + N1;           // N1 fp32
    ushort* h_bf   = (ushort*)(nf + N1);   // N1
    ushort* act_bf = h_bf + N1;            // N1
    ushort* nb_bf  = act_bf + N1;          // N1 (nf_bf round 0, then context)
    ushort* att_bf = nb_bf + N1;           // N1 (act_t / feat_t, bf16 only)
    ushort* gi_bf  = att_bf + N1;          // BS*768
    ushort* gh_bf  = gi_bf + (size_t)BS * 768;
    ushort* attW_bf = gh_bf + (size_t)BS * 768;
    ushort* wih_bf  = attW_bf + 3 * 256 * 256;
    ushort* whh_bf  = wih_bf + 3 * 768 * 256;
    ushort* saW2_bf = whh_bf + 3 * 768 * 256;
    float* smalls = (float*)(saW2_bf + 256 * 256);
    float* ca   = smalls;            // BS
    float* cb   = ca + BS;           // BS
    float* scor = cb + BS;           // BS
    float* wbuf = scor + BS;         // BS
    float* seqf = wbuf + BS;         // B*256
    float* amol = seqf + B * 256;    // B*256
    float* mdot = amol + B * 256;    // B (pad 1024)
    float* sctx = mdot + 1024;       // B*256
    float* g    = sctx + B * 256;    // B*1536
    float* part = g + B * 1536;      // B*NC*256

    cvt_kernel<<<(3 * 256 * 256) / 1024, 256, 0, stream>>>(attendW, attW_bf, (3 * 256 * 256) / 4);
    cvt_kernel<<<(3 * 768 * 256) / 1024, 256, 0, stream>>>(gruWih, wih_bf, (3 * 768 * 256) / 4);
    cvt_kernel<<<(3 * 768 * 256) / 1024, 256, 0, stream>>>(gruWhh, whh_bf, (3 * 768 * 256) / 4);
    cvt_kernel<<<(256 * 256) / 1024, 256, 0, stream>>>(seqAttW, saW2_bf, (256 * 256) / 4);

    embed_kernel<<<BS / 16, 256, 0, stream>>>(amino, embW, embB, neighW, neighB,
                                              h, nf, h_bf, nb_bf);

    for (int d = 0; d < 3; ++d) {
        const float*  cur_f  = (d == 0) ? h : act;
        const float*  nbr_f  = (d == 0) ? nf : act;
        const ushort* nbr_bf = (d == 0) ? nb_bf : act_bf;
        rowdots_kernel<<<BS / 4, 256, 0, stream>>>(cur_f, nbr_f, alignW + d * 512, ca, cb);
        dim3 g1(BS / 128, 256 / 128);
        gemm_mfma_kernel<<<g1, 256, 0, stream>>>(nbr_bf, attW_bf + d * 256 * 256,
                                                 attendB + d * 256, (float*)nullptr, att_bf,
                                                 BS, 256, 256);
        attn_kernel<<<BS / 4, 256, 0, stream>>>(deg, ca, cb, att_bf, alignB, d, nb_bf, S);
        dim3 g2(BS / 128, 768 / 128);
        gemm_mfma_kernel<<<g2, 256, 0, stream>>>(nb_bf, wih_bf + d * 768 * 256,
                                                 gruBih + d * 768, (float*)nullptr, gi_bf,
                                                 BS, 768, 256);
        gemm_mfma_kernel<<<g2, 256, 0, stream>>>(h_bf, whh_bf + d * 768 * 256,
                                                 gruBhh + d * 768, (float*)nullptr, gh_bf,
                                                 BS, 768, 256);
        gru_gate_kernel<<<BS, 256, 0, stream>>>(gi_bf, gh_bf, h, act, h_bf, act_bf);
    }

    seqpool_partial_kernel<<<B * NC, 256, 0, stream>>>(act, mask, part, S, CH);
    seqpool_combine_kernel<<<B, 256, 0, stream>>>(part, saW, seqf, amol, mdot, NC);
    seqscore_kernel<<<BS / 4, 256, 0, stream>>>(act, saW, saB, mdot, mask, scor, S);
    dim3 g3(BS / 128, 256 / 128);
    gemm_mfma_kernel<<<g3, 256, 0, stream>>>(act_bf, saW2_bf, seqAttB, (float*)nullptr, att_bf,
                                             BS, 256, 256);
    seqsm_kernel<<<B, 256, 0, stream>>>(scor, mask, wbuf, S);
    seqctx_partial_kernel<<<B * NC, 256, 0, stream>>>(wbuf, att_bf, part, S, CH);
    seqctx_combine_kernel<<<B, 256, 0, stream>>>(part, sctx, NC);

    for (int t = 0; t < 2; ++t) {
        sgru_mm_kernel<<<B * 1536 / 4, 256, 0, stream>>>(sctx, seqf, sWih, sWhh, sBih, sBhh, g);
        sgru_gate_kernel<<<B, 256, 0, stream>>>(g, seqf, out);
    }
}

// Round 5
// 363.238 us; speedup vs baseline: 3.7798x; 1.1063x over previous
//
#include <hip/hip_runtime.h>
#include <hip/hip_bf16.h>
#include <math.h>

// ProGAT: B=32, S=512, K=21, F_in=26, E=256, R=3, T=2
// Round 4: embed rewrite (weights in regs, no LDS conflicts); rowdots/seqscore folded
// into gru_gate (act dots computed in-register); fp32 act/nf buffers eliminated
// (bf16 consumers); single cvt launch.

#define NEGC (-9.0e8f)

typedef __attribute__((ext_vector_type(8))) short bf16x8;
typedef __attribute__((ext_vector_type(4))) float f32x4;

__device__ __forceinline__ ushort f2bf(float x) {
    union { float f; unsigned u; } v; v.f = x;
    unsigned r = v.u + 0x7FFF + ((v.u >> 16) & 1);
    return (ushort)(r >> 16);
}
__device__ __forceinline__ float bf2f(ushort u) {
    union { unsigned u; float f; } v; v.u = ((unsigned)u) << 16;
    return v.f;
}
__device__ __forceinline__ float sigm_fast(float x) {
    return 1.f / (1.f + __expf(-x));
}
__device__ __forceinline__ float tanh_fast(float x) {
    return 1.f - 2.f / (__expf(2.f * x) + 1.f);
}
__device__ __forceinline__ float elu_fast(float x) {
    return x > 0.f ? x : (__expf(x) - 1.f);
}

typedef const __attribute__((address_space(1))) void gvoid_t;
typedef __attribute__((address_space(3))) void lvoid_t;

// one launch converts all four weight tensors to bf16 (i in ushort4 units)
__global__ __launch_bounds__(256) void cvt4_kernel(
    const float* __restrict__ s0, ushort* __restrict__ d0, int n0,
    const float* __restrict__ s1, ushort* __restrict__ d1, int n1,
    const float* __restrict__ s2, ushort* __restrict__ d2, int n2,
    const float* __restrict__ s3, ushort* __restrict__ d3, int n3)
{
    int i = blockIdx.x * 256 + threadIdx.x;
    const float* s; ushort* dst; int l;
    if (i < n0) { s = s0; dst = d0; l = i; }
    else if (i < n0 + n1) { s = s1; dst = d1; l = i - n0; }
    else if (i < n0 + n1 + n2) { s = s2; dst = d2; l = i - n0 - n1; }
    else if (i < n0 + n1 + n2 + n3) { s = s3; dst = d3; l = i - n0 - n1 - n2; }
    else return;
    float4 v = *reinterpret_cast<const float4*>(s + (size_t)l * 4);
    ushort4 o; o.x = f2bf(v.x); o.y = f2bf(v.y); o.z = f2bf(v.z); o.w = f2bf(v.w);
    *reinterpret_cast<ushort4*>(dst + (size_t)l * 4) = o;
}

// ---------------- bf16 MFMA GEMM: C[M,N] = A[M,K] @ W[N,K]^T + bias ----------------
__global__ __launch_bounds__(256) void gemm_mfma_kernel(
    const ushort* __restrict__ A, const ushort* __restrict__ W,
    const float* __restrict__ bias, float* __restrict__ Cf,
    ushort* __restrict__ Cb, int M, int N, int K)
{
    __shared__ __align__(16) short As[128 * 32];
    __shared__ __align__(16) short Bs[128 * 32];
    int tid = threadIdx.x;
    int lane = tid & 63;
    int w = tid >> 6;
    int wr = w >> 1, wc = w & 1;
    int bm = blockIdx.x * 128;
    int bn = blockIdx.y * 128;

    f32x4 acc[4][4];
#pragma unroll
    for (int m = 0; m < 4; ++m)
#pragma unroll
        for (int n = 0; n < 4; ++n) acc[m][n] = (f32x4){0.f, 0.f, 0.f, 0.f};

    for (int k0 = 0; k0 < K; k0 += 32) {
#pragma unroll
        for (int i = 0; i < 2; ++i) {
            int e = w * 1024 + i * 512 + lane * 8;
            int r = e >> 5, c = e & 31;
            const ushort* ga = A + (size_t)(bm + r) * K + (k0 + c);
            const ushort* gw = W + (size_t)(bn + r) * K + (k0 + c);
            __builtin_amdgcn_global_load_lds((gvoid_t*)ga, (lvoid_t*)&As[w * 1024 + i * 512], 16, 0, 0);
            __builtin_amdgcn_global_load_lds((gvoid_t*)gw, (lvoid_t*)&Bs[w * 1024 + i * 512], 16, 0, 0);
        }
        __syncthreads();
        bf16x8 af[4], bw[4];
        int ra = wr * 64 + (lane & 15);
        int rb = wc * 64 + (lane & 15);
        int kc = (lane >> 4) * 8;
#pragma unroll
        for (int m = 0; m < 4; ++m)
            af[m] = *reinterpret_cast<const bf16x8*>(&As[(ra + m * 16) * 32 + kc]);
#pragma unroll
        for (int n = 0; n < 4; ++n)
            bw[n] = *reinterpret_cast<const bf16x8*>(&Bs[(rb + n * 16) * 32 + kc]);
#pragma unroll
        for (int m = 0; m < 4; ++m)
#pragma unroll
            for (int n = 0; n < 4; ++n)
                acc[m][n] = __builtin_amdgcn_mfma_f32_16x16x32_bf16(af[m], bw[n], acc[m][n], 0, 0, 0);
        __syncthreads();
    }

    int cr0 = bm + wr * 64 + ((lane >> 4) * 4);
    int cc0 = bn + wc * 64 + (lane & 15);
#pragma unroll
    for (int n = 0; n < 4; ++n) {
        int col = cc0 + n * 16;
        float bv = bias[col];
#pragma unroll
        for (int m = 0; m < 4; ++m) {
            int row0 = cr0 + m * 16;
#pragma unroll
            for (int j = 0; j < 4; ++j) {
                float v = acc[m][n][j] + bv;
                size_t idx = (size_t)(row0 + j) * N + col;
                if (Cf) Cf[idx] = v;
                if (Cb) Cb[idx] = f2bf(v);
            }
        }
    }
}

// ---------------- embed: weights in registers, broadcast-only LDS ----------------
__global__ __launch_bounds__(256) void embed_kernel(
    const float* __restrict__ amino, const float* __restrict__ embW,
    const float* __restrict__ embB, const float* __restrict__ neighW,
    const float* __restrict__ neighB,
    float* __restrict__ h, ushort* __restrict__ h_bf, ushort* __restrict__ nf_bf)
{
    const int FIN = 26, FPAD = 28, ROWS = 64;
    __shared__ __align__(16) float xs[ROWS][FPAD];
    int tid = threadIdx.x;
    float wE[FPAD], wN[FPAD];
#pragma unroll
    for (int f = 0; f < FIN; ++f) {
        wE[f] = embW[tid * FIN + f];
        wN[f] = neighW[tid * FIN + f];
    }
    wE[26] = wE[27] = wN[26] = wN[27] = 0.f;
    float b1 = embB[tid], b2 = neighB[tid];
    int row0 = blockIdx.x * ROWS;
    for (int idx = tid; idx < ROWS * FPAD; idx += 256) {
        int r = idx / FPAD, f = idx - r * FPAD;
        xs[r][f] = (f < FIN) ? amino[(size_t)(row0 + r) * FIN + f] : 0.f;
    }
    __syncthreads();
    for (int r = 0; r < ROWS; ++r) {
        const float4* x4 = reinterpret_cast<const float4*>(xs[r]);
        float a = b1, c = b2;
#pragma unroll
        for (int q = 0; q < 7; ++q) {
            float4 x = x4[q];
            a = fmaf(x.x, wE[4 * q], a);     c = fmaf(x.x, wN[4 * q], c);
            a = fmaf(x.y, wE[4 * q + 1], a); c = fmaf(x.y, wN[4 * q + 1], c);
            a = fmaf(x.z, wE[4 * q + 2], a); c = fmaf(x.z, wN[4 * q + 2], c);
            a = fmaf(x.w, wE[4 * q + 3], a); c = fmaf(x.w, wN[4 * q + 3], c);
        }
        a = a > 0.f ? a : 0.01f * a;
        c = c > 0.f ? c : 0.01f * c;
        size_t idx = (size_t)(row0 + r) * 256 + tid;
        h[idx] = a;
        h_bf[idx] = f2bf(a);
        nf_bf[idx] = f2bf(c);
    }
}

// round-0 alignment dots from bf16 sources: ca=cur.w[0:256], cb=nbr.w[256:512]
__global__ __launch_bounds__(256) void rowdots_bf16_kernel(
    const ushort* __restrict__ cur, const ushort* __restrict__ nbr,
    const float* __restrict__ alignW, float* __restrict__ ca, float* __restrict__ cb)
{
    int tid = threadIdx.x;
    int wv = tid >> 6, lane = tid & 63;
    size_t row = (size_t)blockIdx.x * 4 + wv;
    int e0 = lane * 4;
    ushort4 cv = *reinterpret_cast<const ushort4*>(cur + row * 256 + e0);
    ushort4 nv = *reinterpret_cast<const ushort4*>(nbr + row * 256 + e0);
    float4 w1 = *reinterpret_cast<const float4*>(alignW + e0);
    float4 w2 = *reinterpret_cast<const float4*>(alignW + 256 + e0);
    float p1 = bf2f(cv.x) * w1.x + bf2f(cv.y) * w1.y + bf2f(cv.z) * w1.z + bf2f(cv.w) * w1.w;
    float p2 = bf2f(nv.x) * w2.x + bf2f(nv.y) * w2.y + bf2f(nv.z) * w2.z + bf2f(nv.w) * w2.w;
#pragma unroll
    for (int off = 32; off > 0; off >>= 1) {
        p1 += __shfl_down(p1, off);
        p2 += __shfl_down(p2, off);
    }
    if (lane == 0) { ca[row] = p1; cb[row] = p2; }
}

// attn: 4 rows/block, one wave per row, bf16 gather, XCD-clustered swizzle
__global__ __launch_bounds__(256) void attn_kernel(
    const int* __restrict__ deg, const float* __restrict__ ca,
    const float* __restrict__ cbrow, const ushort* __restrict__ act_t,
    const float* __restrict__ alignB, int d,
    ushort* __restrict__ context_bf, int S)
{
    const int KNB = 21;
    int raw = blockIdx.x;
    int bid = (raw & 7) * 512 + (raw >> 3);
    int bs0 = bid * 4;
    int b = bs0 >> 9;
    int tid = threadIdx.x;
    int wv = tid >> 6, lane = tid & 63;
    int bs = bs0 + wv;
    __shared__ float ss[4][KNB];
    __shared__ int   sj[4][KNB];
    if (lane < KNB) {
        int j = deg[bs * KNB + lane];
        float cbv = (j >= 0) ? cbrow[b * S + j] : 0.f;
        float sc = ca[bs] + cbv + alignB[d];
        sc = sc > 0.f ? sc : 0.01f * sc;
        if (j < 0) sc += NEGC;
        sj[wv][lane] = j;
        ss[wv][lane] = sc;
    }
    __syncthreads();
    float mx = -3.4e38f;
#pragma unroll
    for (int k = 0; k < KNB; ++k) mx = fmaxf(mx, ss[wv][k]);
    float se[KNB];
    float sum = 0.f;
#pragma unroll
    for (int k = 0; k < KNB; ++k) { se[k] = __expf(ss[wv][k] - mx); sum += se[k]; }
    float inv = 1.f / sum;
    const ushort* base = act_t + (size_t)b * S * 256 + lane * 4;
    float a0 = 0.f, a1 = 0.f, a2 = 0.f, a3 = 0.f;
#pragma unroll
    for (int k = 0; k < KNB; ++k) {
        int j = sj[wv][k];
        if (j >= 0) {
            ushort4 v = *reinterpret_cast<const ushort4*>(base + (size_t)j * 256);
            float wk = se[k];
            a0 = fmaf(wk, bf2f(v.x), a0);
            a1 = fmaf(wk, bf2f(v.y), a1);
            a2 = fmaf(wk, bf2f(v.z), a2);
            a3 = fmaf(wk, bf2f(v.w), a3);
        }
    }
    ushort4 o;
    o.x = f2bf(elu_fast(a0 * inv));
    o.y = f2bf(elu_fast(a1 * inv));
    o.z = f2bf(elu_fast(a2 * inv));
    o.w = f2bf(elu_fast(a3 * inv));
    *reinterpret_cast<ushort4*>(&context_bf[(size_t)bs * 256 + lane * 4]) = o;
}

// GRU gate, 4 rows/block, + in-register alignment dots for the NEXT round
// (w1/out1 always set; w2/out2 nullptr on last round where only p=act.saW is needed)
__global__ __launch_bounds__(256) void gru_gate_kernel(
    const ushort* __restrict__ gi, const ushort* __restrict__ gh,
    float* __restrict__ h, ushort* __restrict__ h_bf, ushort* __restrict__ act_bf,
    const float* __restrict__ w1, const float* __restrict__ w2,
    float* __restrict__ out1, float* __restrict__ out2)
{
    int tid = threadIdx.x;
    int wv = tid >> 6, lane = tid & 63;
    size_t row = (size_t)blockIdx.x * 4 + wv;
    int e0 = lane * 4;
    const ushort* gir = gi + row * 768;
    const ushort* ghr = gh + row * 768;
    ushort4 ir = *reinterpret_cast<const ushort4*>(gir + e0);
    ushort4 iz = *reinterpret_cast<const ushort4*>(gir + 256 + e0);
    ushort4 in_ = *reinterpret_cast<const ushort4*>(gir + 512 + e0);
    ushort4 hr = *reinterpret_cast<const ushort4*>(ghr + e0);
    ushort4 hz = *reinterpret_cast<const ushort4*>(ghr + 256 + e0);
    ushort4 hn = *reinterpret_cast<const ushort4*>(ghr + 512 + e0);
    float4 h4 = *reinterpret_cast<const float4*>(h + row * 256 + e0);
    ushort ira[4] = {ir.x, ir.y, ir.z, ir.w};
    ushort iza[4] = {iz.x, iz.y, iz.z, iz.w};
    ushort ina[4] = {in_.x, in_.y, in_.z, in_.w};
    ushort hra[4] = {hr.x, hr.y, hr.z, hr.w};
    ushort hza[4] = {hz.x, hz.y, hz.z, hz.w};
    ushort hna[4] = {hn.x, hn.y, hn.z, hn.w};
    float hv[4] = {h4.x, h4.y, h4.z, h4.w};
    float hnew[4], acta[4];
#pragma unroll
    for (int j = 0; j < 4; ++j) {
        float r = sigm_fast(bf2f(ira[j]) + bf2f(hra[j]));
        float z = sigm_fast(bf2f(iza[j]) + bf2f(hza[j]));
        float n = tanh_fast(bf2f(ina[j]) + r * bf2f(hna[j]));
        float hh = (1.f - z) * n + z * hv[j];
        hnew[j] = hh;
        acta[j] = fmaxf(hh, 0.f);
    }
    float4 ho = {hnew[0], hnew[1], hnew[2], hnew[3]};
    *reinterpret_cast<float4*>(h + row * 256 + e0) = ho;
    ushort4 hb = {f2bf(hnew[0]), f2bf(hnew[1]), f2bf(hnew[2]), f2bf(hnew[3])};
    *reinterpret_cast<ushort4*>(h_bf + row * 256 + e0) = hb;
    ushort4 ab = {f2bf(acta[0]), f2bf(acta[1]), f2bf(acta[2]), f2bf(acta[3])};
    *reinterpret_cast<ushort4*>(act_bf + row * 256 + e0) = ab;

    float4 w1v = *reinterpret_cast<const float4*>(w1 + e0);
    float p1 = acta[0] * w1v.x + acta[1] * w1v.y + acta[2] * w1v.z + acta[3] * w1v.w;
#pragma unroll
    for (int off = 32; off > 0; off >>= 1) p1 += __shfl_down(p1, off);
    if (w2) {
        float4 w2v = *reinterpret_cast<const float4*>(w2 + e0);
        float p2 = acta[0] * w2v.x + acta[1] * w2v.y + acta[2] * w2v.z + acta[3] * w2v.w;
#pragma unroll
        for (int off = 32; off > 0; off >>= 1) p2 += __shfl_down(p2, off);
        if (lane == 0) { out1[row] = p1; out2[row] = p2; }
    } else {
        if (lane == 0) out1[row] = p1;
    }
}

// ---------- seqpool: two-stage (bf16 act) ----------
__global__ __launch_bounds__(256) void seqpool_partial_kernel(
    const ushort* __restrict__ act, const float* __restrict__ mask,
    float* __restrict__ partial, int S, int CH)
{
    int bc = blockIdx.x;
    int NC = S / CH;
    int b = bc / NC, c = bc - b * NC;
    int tid = threadIdx.x;
    int s0 = c * CH;
    const ushort* ab = act + ((size_t)b * S + s0) * 256;
    const float* mb = mask + b * S + s0;
    float acc = 0.f;
    for (int s = 0; s < CH; ++s)
        acc = fmaf(bf2f(ab[(size_t)s * 256 + tid]), mb[s], acc);
    partial[(size_t)bc * 256 + tid] = acc;
}
__global__ __launch_bounds__(256) void seqpool_combine_kernel(
    const float* __restrict__ partial, const float* __restrict__ saW,
    float* __restrict__ seqfeat, float* __restrict__ moldot, int NC)
{
    int b = blockIdx.x, tid = threadIdx.x;
    int lane = tid & 63, wv = tid >> 6;
    __shared__ float red[4];
    float acc = 0.f;
    for (int c = 0; c < NC; ++c)
        acc += partial[((size_t)b * NC + c) * 256 + tid];
    seqfeat[b * 256 + tid] = acc;
    float am = fmaxf(acc, 0.f);
    float p = am * saW[tid];
#pragma unroll
    for (int off = 32; off > 0; off >>= 1) p += __shfl_down(p, off);
    if (lane == 0) red[wv] = p;
    __syncthreads();
    if (tid == 0) moldot[b] = red[0] + red[1] + red[2] + red[3];
}

// finish score (leaky(mdot + praw + b) + mask NEG) then softmax -> weights
__global__ __launch_bounds__(256) void seqsm_kernel(
    const float* __restrict__ praw, const float* __restrict__ mdot,
    const float* __restrict__ sab, const float* __restrict__ mask,
    float* __restrict__ wout, int S)
{
    int b = blockIdx.x;
    int tid = threadIdx.x;
    int lane = tid & 63, wv = tid >> 6;
    __shared__ float sw[512];
    __shared__ float r1[4], r2[4];
    float md = mdot[b], sb = sab[0];
    float lm = -3.4e38f;
    for (int s = tid; s < S; s += 256) {
        float sc = md + praw[b * S + s] + sb;
        sc = sc > 0.f ? sc : 0.01f * sc;
        if (mask[b * S + s] == 0.f) sc += NEGC;
        sw[s] = sc;
        lm = fmaxf(lm, sc);
    }
#pragma unroll
    for (int off = 32; off > 0; off >>= 1) lm = fmaxf(lm, __shfl_down(lm, off));
    if (lane == 0) r1[wv] = lm;
    __syncthreads();
    float mx = fmaxf(fmaxf(r1[0], r1[1]), fmaxf(r1[2], r1[3]));
    float ls = 0.f;
    for (int s = tid; s < S; s += 256) {
        float e = __expf(sw[s] - mx);
        sw[s] = e * mask[b * S + s];
        ls += e;
    }
#pragma unroll
    for (int off = 32; off > 0; off >>= 1) ls += __shfl_down(ls, off);
    if (lane == 0) r2[wv] = ls;
    __syncthreads();
    float inv = 1.f / (r2[0] + r2[1] + r2[2] + r2[3]);
    for (int s = tid; s < S; s += 256)
        wout[b * S + s] = sw[s] * inv;
}

__global__ __launch_bounds__(256) void seqctx_partial_kernel(
    const float* __restrict__ w, const ushort* __restrict__ feat,
    float* __restrict__ partial, int S, int CH)
{
    int bc = blockIdx.x;
    int NC = S / CH;
    int b = bc / NC, c = bc - b * NC;
    int tid = threadIdx.x;
    int s0 = c * CH;
    const ushort* fb = feat + ((size_t)b * S + s0) * 256;
    const float* wb = w + b * S + s0;
    float acc = 0.f;
    for (int s = 0; s < CH; ++s)
        acc = fmaf(wb[s], bf2f(fb[(size_t)s * 256 + tid]), acc);
    partial[(size_t)bc * 256 + tid] = acc;
}

__global__ __launch_bounds__(256) void seqctx_combine_kernel(
    const float* __restrict__ partial, float* __restrict__ sctx, int NC)
{
    int b = blockIdx.x, tid = threadIdx.x;
    float acc = 0.f;
    for (int c = 0; c < NC; ++c)
        acc += partial[((size_t)b * NC + c) * 256 + tid];
    sctx[b * 256 + tid] = elu_fast(acc);
}

__global__ __launch_bounds__(256) void sgru_mm_kernel(
    const float* __restrict__ x, const float* __restrict__ hseq,
    const float* __restrict__ wih, const float* __restrict__ whh,
    const float* __restrict__ bih, const float* __restrict__ bhh,
    float* __restrict__ g)
{
    int out = blockIdx.x * 4 + (threadIdx.x >> 6);
    int lane = threadIdx.x & 63;
    int b = out / 1536;
    int j = out - b * 1536;
    const float* src; const float* w; const float* bp; int jj;
    if (j < 768) { src = x + b * 256; w = wih; bp = bih; jj = j; }
    else         { src = hseq + b * 256; w = whh; bp = bhh; jj = j - 768; }
    float p = 0.f;
#pragma unroll
    for (int i = 0; i < 4; ++i) {
        int idx = lane + 64 * i;
        p = fmaf(src[idx], w[(size_t)jj * 256 + idx], p);
    }
#pragma unroll
    for (int off = 32; off > 0; off >>= 1) p += __shfl_down(p, off);
    if (lane == 0) g[out] = p + bp[jj];
}

__global__ __launch_bounds__(256) void sgru_gate_kernel(
    const float* __restrict__ g, float* __restrict__ hseq, float* __restrict__ out)
{
    int b = blockIdx.x, e = threadIdx.x;
    const float* gr = g + b * 1536;
    float r = sigm_fast(gr[e] + gr[768 + e]);
    float z = sigm_fast(gr[256 + e] + gr[1024 + e]);
    float n = tanh_fast(gr[512 + e] + r * gr[1280 + e]);
    float hv = hseq[b * 256 + e];
    float hn = (1.f - z) * n + z * hv;
    hseq[b * 256 + e] = hn;
    out[b * 256 + e] = fmaxf(hn, 0.f);
}

extern "C" void kernel_launch(void* const* d_in, const int* in_sizes, int n_in,
                              void* d_out, int out_size, void* d_ws, size_t ws_size,
                              hipStream_t stream)
{
    const float* amino   = (const float*)d_in[0];
    const int*   deg     = (const int*)  d_in[1];
    const float* mask    = (const float*)d_in[2];
    const float* embW    = (const float*)d_in[3];
    const float* embB    = (const float*)d_in[4];
    const float* neighW  = (const float*)d_in[5];
    const float* neighB  = (const float*)d_in[6];
    const float* alignW  = (const float*)d_in[7];
    const float* alignB  = (const float*)d_in[8];
    const float* attendW = (const float*)d_in[9];
    const float* attendB = (const float*)d_in[10];
    const float* gruWih  = (const float*)d_in[11];
    const float* gruWhh  = (const float*)d_in[12];
    const float* gruBih  = (const float*)d_in[13];
    const float* gruBhh  = (const float*)d_in[14];
    const float* saW     = (const float*)d_in[15];
    const float* saB     = (const float*)d_in[16];
    const float* seqAttW = (const float*)d_in[17];
    const float* seqAttB = (const float*)d_in[18];
    const float* sWih    = (const float*)d_in[19];
    const float* sWhh    = (const float*)d_in[20];
    const float* sBih    = (const float*)d_in[21];
    const float* sBhh    = (const float*)d_in[22];
    float* out = (float*)d_out;

    const int B = 32, S = 512;
    const int BS = B * S;                 // 16384
    const size_t N1 = (size_t)BS * 256;   // 4194304
    const int CH = 32, NC = S / CH;       // 16 chunks

    float* ws = (float*)d_ws;
    float* h  = ws;                              // N1 fp32 (GRU state)
    ushort* h_bf   = (ushort*)(h + N1);          // N1
    ushort* act_bf = h_bf + N1;                  // N1
    ushort* nb_bf  = act_bf + N1;                // N1 (nf round 0, then context)
    ushort* att_bf = nb_bf + N1;                 // N1 (act_t / feat_t)
    ushort* gi_bf  = att_bf + N1;                // BS*768
    ushort* gh_bf  = gi_bf + (size_t)BS * 768;
    ushort* attW_bf = gh_bf + (size_t)BS * 768;  // 3*256*256
    ushort* wih_bf  = attW_bf + 3 * 256 * 256;   // 3*768*256
    ushort* whh_bf  = wih_bf + 3 * 768 * 256;
    ushort* saW2_bf = whh_bf + 3 * 768 * 256;    // 256*256
    float* smalls = (float*)(saW2_bf + 256 * 256);
    float* ca   = smalls;            // BS
    float* cb   = ca + BS;           // BS
    float* scor = cb + BS;           // BS (raw act.saW dot)
    float* wbuf = scor + BS;         // BS
    float* seqf = wbuf + BS;         // B*256
    float* mdot = seqf + B * 256;    // B (pad 1024)
    float* sctx = mdot + 1024;       // B*256
    float* g    = sctx + B * 256;    // B*1536
    float* part = g + B * 1536;      // B*NC*256

    const int c0 = (3 * 256 * 256) / 4, c1 = (3 * 768 * 256) / 4,
              c2 = (3 * 768 * 256) / 4, c3 = (256 * 256) / 4;
    cvt4_kernel<<<(c0 + c1 + c2 + c3 + 255) / 256, 256, 0, stream>>>(
        attendW, attW_bf, c0, gruWih, wih_bf, c1, gruWhh, whh_bf, c2, seqAttW, saW2_bf, c3);

    embed_kernel<<<BS / 64, 256, 0, stream>>>(amino, embW, embB, neighW, neighB,
                                              h, h_bf, nb_bf);
    rowdots_bf16_kernel<<<BS / 4, 256, 0, stream>>>(h_bf, nb_bf, alignW, ca, cb);

    for (int d = 0; d < 3; ++d) {
        const ushort* nbr_bf = (d == 0) ? nb_bf : act_bf;
        dim3 g1(BS / 128, 256 / 128);
        gemm_mfma_kernel<<<g1, 256, 0, stream>>>(nbr_bf, attW_bf + d * 256 * 256,
                                                 attendB + d * 256, (float*)nullptr, att_bf,
                                                 BS, 256, 256);
        attn_kernel<<<BS / 4, 256, 0, stream>>>(deg, ca, cb, att_bf, alignB, d, nb_bf, S);
        dim3 g2(BS / 128, 768 / 128);
        gemm_mfma_kernel<<<g2, 256, 0, stream>>>(nb_bf, wih_bf + d * 768 * 256,
                                                 gruBih + d * 768, (float*)nullptr, gi_bf,
                                                 BS, 768, 256);
        gemm_mfma_kernel<<<g2, 256, 0, stream>>>(h_bf, whh_bf + d * 768 * 256,
                                                 gruBhh + d * 768, (float*)nullptr, gh_bf,
                                                 BS, 768, 256);
        if (d < 2) {
            // dots for next round's alignment score (both halves read next-round act)
            gru_gate_kernel<<<BS / 4, 256, 0, stream>>>(gi_bf, gh_bf, h, h_bf, act_bf,
                                                        alignW + (d + 1) * 512,
                                                        alignW + (d + 1) * 512 + 256, ca, cb);
        } else {
            // last round: single dot act.saW[256:512] -> raw seq score
            gru_gate_kernel<<<BS / 4, 256, 0, stream>>>(gi_bf, gh_bf, h, h_bf, act_bf,
                                                        saW + 256, (float*)nullptr,
                                                        scor, (float*)nullptr);
        }
    }

    seqpool_partial_kernel<<<B * NC, 256, 0, stream>>>(act_bf, mask, part, S, CH);
    seqpool_combine_kernel<<<B, 256, 0, stream>>>(part, saW, seqf, mdot, NC);
    dim3 g3(BS / 128, 256 / 128);
    gemm_mfma_kernel<<<g3, 256, 0, stream>>>(act_bf, saW2_bf, seqAttB, (float*)nullptr, att_bf,
                                             BS, 256, 256);
    seqsm_kernel<<<B, 256, 0, stream>>>(scor, mdot, saB, mask, wbuf, S);
    seqctx_partial_kernel<<<B * NC, 256, 0, stream>>>(wbuf, att_bf, part, S, CH);
    seqctx_combine_kernel<<<B, 256, 0, stream>>>(part, sctx, NC);

    for (int t = 0; t < 2; ++t) {
        sgru_mm_kernel<<<B * 1536 / 4, 256, 0, stream>>>(sctx, seqf, sWih, sWhh, sBih, sBhh, g);
        sgru_gate_kernel<<<B, 256, 0, stream>>>(g, seqf, out);
    }
}

// Round 6
// 287.943 us; speedup vs baseline: 4.7682x; 1.2615x over previous
//
#include <hip/hip_runtime.h>
#include <hip/hip_bf16.h>
#include <math.h>

// ProGAT: B=32, S=512, K=21, F_in=26, E=256, R=3, T=2
// Round 5: h bf16-only (fp32 master dropped); dual-job GEMM (attend+gh merged per round)
// with flattened grid + bijective XCD swizzle (A-panel L2 reuse); seqpool_combine+softmax
// fused; sgru reuses the loop-invariant gi half.

#define NEGC (-9.0e8f)

typedef __attribute__((ext_vector_type(8))) short bf16x8;
typedef __attribute__((ext_vector_type(4))) float f32x4;

__device__ __forceinline__ ushort f2bf(float x) {
    union { float f; unsigned u; } v; v.f = x;
    unsigned r = v.u + 0x7FFF + ((v.u >> 16) & 1);
    return (ushort)(r >> 16);
}
__device__ __forceinline__ float bf2f(ushort u) {
    union { unsigned u; float f; } v; v.u = ((unsigned)u) << 16;
    return v.f;
}
__device__ __forceinline__ float sigm_fast(float x) {
    return 1.f / (1.f + __expf(-x));
}
__device__ __forceinline__ float tanh_fast(float x) {
    return 1.f - 2.f / (__expf(2.f * x) + 1.f);
}
__device__ __forceinline__ float elu_fast(float x) {
    return x > 0.f ? x : (__expf(x) - 1.f);
}

typedef const __attribute__((address_space(1))) void gvoid_t;
typedef __attribute__((address_space(3))) void lvoid_t;

// one launch converts all four weight tensors to bf16 (i in ushort4 units)
__global__ __launch_bounds__(256) void cvt4_kernel(
    const float* __restrict__ s0, ushort* __restrict__ d0, int n0,
    const float* __restrict__ s1, ushort* __restrict__ d1, int n1,
    const float* __restrict__ s2, ushort* __restrict__ d2, int n2,
    const float* __restrict__ s3, ushort* __restrict__ d3, int n3)
{
    int i = blockIdx.x * 256 + threadIdx.x;
    const float* s; ushort* dst; int l;
    if (i < n0) { s = s0; dst = d0; l = i; }
    else if (i < n0 + n1) { s = s1; dst = d1; l = i - n0; }
    else if (i < n0 + n1 + n2) { s = s2; dst = d2; l = i - n0 - n1; }
    else if (i < n0 + n1 + n2 + n3) { s = s3; dst = d3; l = i - n0 - n1 - n2; }
    else return;
    float4 v = *reinterpret_cast<const float4*>(s + (size_t)l * 4);
    ushort4 o; o.x = f2bf(v.x); o.y = f2bf(v.y); o.z = f2bf(v.z); o.w = f2bf(v.w);
    *reinterpret_cast<ushort4*>(dst + (size_t)l * 4) = o;
}

// ---------------- dual-job bf16 MFMA GEMM ----------------
// Job0: C0[M x n0t*128] = A0 @ W0^T + b0; Job1 likewise. M = 16384 (128 row-tiles).
// Flat grid of 128*(n0t+n1t) blocks; XCD-swizzled, bn-fastest so same-bm blocks
// (sharing the A panel) land on one XCD's L2.
__global__ __launch_bounds__(256) void gemm_dual_kernel(
    const ushort* __restrict__ A0, const ushort* __restrict__ W0,
    const float* __restrict__ b0, ushort* __restrict__ C0, int n0t,
    const ushort* __restrict__ A1, const ushort* __restrict__ W1,
    const float* __restrict__ b1, ushort* __restrict__ C1, int n1t,
    int K)
{
    __shared__ __align__(16) short As[128 * 32];
    __shared__ __align__(16) short Bs[128 * 32];
    int nwg = gridDim.x;
    int q = nwg >> 3;                       // nwg always divisible by 8
    int flat = blockIdx.x;
    int sw = (flat & 7) * q + (flat >> 3);  // bijective XCD swizzle
    int tot = n0t + n1t;
    int bmi = sw / tot, bni = sw - bmi * tot;
    const ushort* A; const ushort* W; const float* bias; ushort* C; int N, bn;
    if (bni < n0t) { A = A0; W = W0; bias = b0; C = C0; N = n0t << 7; bn = bni << 7; }
    else { A = A1; W = W1; bias = b1; C = C1; N = n1t << 7; bn = (bni - n0t) << 7; }
    int bm = bmi << 7;

    int tid = threadIdx.x;
    int lane = tid & 63;
    int w = tid >> 6;
    int wr = w >> 1, wc = w & 1;

    f32x4 acc[4][4];
#pragma unroll
    for (int m = 0; m < 4; ++m)
#pragma unroll
        for (int n = 0; n < 4; ++n) acc[m][n] = (f32x4){0.f, 0.f, 0.f, 0.f};

    for (int k0 = 0; k0 < K; k0 += 32) {
#pragma unroll
        for (int i = 0; i < 2; ++i) {
            int e = w * 1024 + i * 512 + lane * 8;
            int r = e >> 5, c = e & 31;
            const ushort* ga = A + (size_t)(bm + r) * K + (k0 + c);
            const ushort* gw = W + (size_t)(bn + r) * K + (k0 + c);
            __builtin_amdgcn_global_load_lds((gvoid_t*)ga, (lvoid_t*)&As[w * 1024 + i * 512], 16, 0, 0);
            __builtin_amdgcn_global_load_lds((gvoid_t*)gw, (lvoid_t*)&Bs[w * 1024 + i * 512], 16, 0, 0);
        }
        __syncthreads();
        bf16x8 af[4], bw[4];
        int ra = wr * 64 + (lane & 15);
        int rb = wc * 64 + (lane & 15);
        int kc = (lane >> 4) * 8;
#pragma unroll
        for (int m = 0; m < 4; ++m)
            af[m] = *reinterpret_cast<const bf16x8*>(&As[(ra + m * 16) * 32 + kc]);
#pragma unroll
        for (int n = 0; n < 4; ++n)
            bw[n] = *reinterpret_cast<const bf16x8*>(&Bs[(rb + n * 16) * 32 + kc]);
#pragma unroll
        for (int m = 0; m < 4; ++m)
#pragma unroll
            for (int n = 0; n < 4; ++n)
                acc[m][n] = __builtin_amdgcn_mfma_f32_16x16x32_bf16(af[m], bw[n], acc[m][n], 0, 0, 0);
        __syncthreads();
    }

    int cr0 = bm + wr * 64 + ((lane >> 4) * 4);
    int cc0 = bn + wc * 64 + (lane & 15);
#pragma unroll
    for (int n = 0; n < 4; ++n) {
        int col = cc0 + n * 16;
        float bv = bias[col - bn + (bn)];   // bias indexed by absolute col
        bv = bias[col];
#pragma unroll
        for (int m = 0; m < 4; ++m) {
            int row0 = cr0 + m * 16;
#pragma unroll
            for (int j = 0; j < 4; ++j) {
                float v = acc[m][n][j] + bv;
                C[(size_t)(row0 + j) * N + col] = f2bf(v);
            }
        }
    }
}

// ---------------- embed: weights in registers, broadcast-only LDS ----------------
__global__ __launch_bounds__(256) void embed_kernel(
    const float* __restrict__ amino, const float* __restrict__ embW,
    const float* __restrict__ embB, const float* __restrict__ neighW,
    const float* __restrict__ neighB,
    ushort* __restrict__ h_bf, ushort* __restrict__ nf_bf)
{
    const int FIN = 26, FPAD = 28, ROWS = 64;
    __shared__ __align__(16) float xs[ROWS][FPAD];
    int tid = threadIdx.x;
    float wE[FPAD], wN[FPAD];
#pragma unroll
    for (int f = 0; f < FIN; ++f) {
        wE[f] = embW[tid * FIN + f];
        wN[f] = neighW[tid * FIN + f];
    }
    wE[26] = wE[27] = wN[26] = wN[27] = 0.f;
    float b1 = embB[tid], b2 = neighB[tid];
    int row0 = blockIdx.x * ROWS;
    for (int idx = tid; idx < ROWS * FPAD; idx += 256) {
        int r = idx / FPAD, f = idx - r * FPAD;
        xs[r][f] = (f < FIN) ? amino[(size_t)(row0 + r) * FIN + f] : 0.f;
    }
    __syncthreads();
    for (int r = 0; r < ROWS; ++r) {
        const float4* x4 = reinterpret_cast<const float4*>(xs[r]);
        float a = b1, c = b2;
#pragma unroll
        for (int q = 0; q < 7; ++q) {
            float4 x = x4[q];
            a = fmaf(x.x, wE[4 * q], a);     c = fmaf(x.x, wN[4 * q], c);
            a = fmaf(x.y, wE[4 * q + 1], a); c = fmaf(x.y, wN[4 * q + 1], c);
            a = fmaf(x.z, wE[4 * q + 2], a); c = fmaf(x.z, wN[4 * q + 2], c);
            a = fmaf(x.w, wE[4 * q + 3], a); c = fmaf(x.w, wN[4 * q + 3], c);
        }
        a = a > 0.f ? a : 0.01f * a;
        c = c > 0.f ? c : 0.01f * c;
        size_t idx = (size_t)(row0 + r) * 256 + tid;
        h_bf[idx] = f2bf(a);
        nf_bf[idx] = f2bf(c);
    }
}

// round-0 alignment dots from bf16 sources
__global__ __launch_bounds__(256) void rowdots_bf16_kernel(
    const ushort* __restrict__ cur, const ushort* __restrict__ nbr,
    const float* __restrict__ alignW, float* __restrict__ ca, float* __restrict__ cb)
{
    int tid = threadIdx.x;
    int wv = tid >> 6, lane = tid & 63;
    size_t row = (size_t)blockIdx.x * 4 + wv;
    int e0 = lane * 4;
    ushort4 cv = *reinterpret_cast<const ushort4*>(cur + row * 256 + e0);
    ushort4 nv = *reinterpret_cast<const ushort4*>(nbr + row * 256 + e0);
    float4 w1 = *reinterpret_cast<const float4*>(alignW + e0);
    float4 w2 = *reinterpret_cast<const float4*>(alignW + 256 + e0);
    float p1 = bf2f(cv.x) * w1.x + bf2f(cv.y) * w1.y + bf2f(cv.z) * w1.z + bf2f(cv.w) * w1.w;
    float p2 = bf2f(nv.x) * w2.x + bf2f(nv.y) * w2.y + bf2f(nv.z) * w2.z + bf2f(nv.w) * w2.w;
#pragma unroll
    for (int off = 32; off > 0; off >>= 1) {
        p1 += __shfl_down(p1, off);
        p2 += __shfl_down(p2, off);
    }
    if (lane == 0) { ca[row] = p1; cb[row] = p2; }
}

// attn: 4 rows/block, one wave per row, bf16 gather, XCD-clustered swizzle
__global__ __launch_bounds__(256) void attn_kernel(
    const int* __restrict__ deg, const float* __restrict__ ca,
    const float* __restrict__ cbrow, const ushort* __restrict__ act_t,
    const float* __restrict__ alignB, int d,
    ushort* __restrict__ context_bf, int S)
{
    const int KNB = 21;
    int raw = blockIdx.x;
    int bid = (raw & 7) * 512 + (raw >> 3);
    int bs0 = bid * 4;
    int b = bs0 >> 9;
    int tid = threadIdx.x;
    int wv = tid >> 6, lane = tid & 63;
    int bs = bs0 + wv;
    __shared__ float ss[4][KNB];
    __shared__ int   sj[4][KNB];
    if (lane < KNB) {
        int j = deg[bs * KNB + lane];
        float cbv = (j >= 0) ? cbrow[b * S + j] : 0.f;
        float sc = ca[bs] + cbv + alignB[d];
        sc = sc > 0.f ? sc : 0.01f * sc;
        if (j < 0) sc += NEGC;
        sj[wv][lane] = j;
        ss[wv][lane] = sc;
    }
    __syncthreads();
    float mx = -3.4e38f;
#pragma unroll
    for (int k = 0; k < KNB; ++k) mx = fmaxf(mx, ss[wv][k]);
    float se[KNB];
    float sum = 0.f;
#pragma unroll
    for (int k = 0; k < KNB; ++k) { se[k] = __expf(ss[wv][k] - mx); sum += se[k]; }
    float inv = 1.f / sum;
    const ushort* base = act_t + (size_t)b * S * 256 + lane * 4;
    float a0 = 0.f, a1 = 0.f, a2 = 0.f, a3 = 0.f;
#pragma unroll
    for (int k = 0; k < KNB; ++k) {
        int j = sj[wv][k];
        if (j >= 0) {
            ushort4 v = *reinterpret_cast<const ushort4*>(base + (size_t)j * 256);
            float wk = se[k];
            a0 = fmaf(wk, bf2f(v.x), a0);
            a1 = fmaf(wk, bf2f(v.y), a1);
            a2 = fmaf(wk, bf2f(v.z), a2);
            a3 = fmaf(wk, bf2f(v.w), a3);
        }
    }
    ushort4 o;
    o.x = f2bf(elu_fast(a0 * inv));
    o.y = f2bf(elu_fast(a1 * inv));
    o.z = f2bf(elu_fast(a2 * inv));
    o.w = f2bf(elu_fast(a3 * inv));
    *reinterpret_cast<ushort4*>(&context_bf[(size_t)bs * 256 + lane * 4]) = o;
}

// GRU gate (bf16 h state), 4 rows/block, + in-register alignment dots for next round
__global__ __launch_bounds__(256) void gru_gate_kernel(
    const ushort* __restrict__ gi, const ushort* __restrict__ gh,
    ushort* __restrict__ h_bf, ushort* __restrict__ act_bf,
    const float* __restrict__ w1, const float* __restrict__ w2,
    float* __restrict__ out1, float* __restrict__ out2)
{
    int tid = threadIdx.x;
    int wv = tid >> 6, lane = tid & 63;
    size_t row = (size_t)blockIdx.x * 4 + wv;
    int e0 = lane * 4;
    const ushort* gir = gi + row * 768;
    const ushort* ghr = gh + row * 768;
    ushort4 ir = *reinterpret_cast<const ushort4*>(gir + e0);
    ushort4 iz = *reinterpret_cast<const ushort4*>(gir + 256 + e0);
    ushort4 in_ = *reinterpret_cast<const ushort4*>(gir + 512 + e0);
    ushort4 hr = *reinterpret_cast<const ushort4*>(ghr + e0);
    ushort4 hz = *reinterpret_cast<const ushort4*>(ghr + 256 + e0);
    ushort4 hn = *reinterpret_cast<const ushort4*>(ghr + 512 + e0);
    ushort4 h4 = *reinterpret_cast<const ushort4*>(h_bf + row * 256 + e0);
    ushort ira[4] = {ir.x, ir.y, ir.z, ir.w};
    ushort iza[4] = {iz.x, iz.y, iz.z, iz.w};
    ushort ina[4] = {in_.x, in_.y, in_.z, in_.w};
    ushort hra[4] = {hr.x, hr.y, hr.z, hr.w};
    ushort hza[4] = {hz.x, hz.y, hz.z, hz.w};
    ushort hna[4] = {hn.x, hn.y, hn.z, hn.w};
    ushort hba[4] = {h4.x, h4.y, h4.z, h4.w};
    float hnew[4], acta[4];
#pragma unroll
    for (int j = 0; j < 4; ++j) {
        float r = sigm_fast(bf2f(ira[j]) + bf2f(hra[j]));
        float z = sigm_fast(bf2f(iza[j]) + bf2f(hza[j]));
        float n = tanh_fast(bf2f(ina[j]) + r * bf2f(hna[j]));
        float hh = (1.f - z) * n + z * bf2f(hba[j]);
        hnew[j] = hh;
        acta[j] = fmaxf(hh, 0.f);
    }
    ushort4 hb = {f2bf(hnew[0]), f2bf(hnew[1]), f2bf(hnew[2]), f2bf(hnew[3])};
    *reinterpret_cast<ushort4*>(h_bf + row * 256 + e0) = hb;
    ushort4 ab = {f2bf(acta[0]), f2bf(acta[1]), f2bf(acta[2]), f2bf(acta[3])};
    *reinterpret_cast<ushort4*>(act_bf + row * 256 + e0) = ab;

    float4 w1v = *reinterpret_cast<const float4*>(w1 + e0);
    float p1 = acta[0] * w1v.x + acta[1] * w1v.y + acta[2] * w1v.z + acta[3] * w1v.w;
#pragma unroll
    for (int off = 32; off > 0; off >>= 1) p1 += __shfl_down(p1, off);
    if (w2) {
        float4 w2v = *reinterpret_cast<const float4*>(w2 + e0);
        float p2 = acta[0] * w2v.x + acta[1] * w2v.y + acta[2] * w2v.z + acta[3] * w2v.w;
#pragma unroll
        for (int off = 32; off > 0; off >>= 1) p2 += __shfl_down(p2, off);
        if (lane == 0) { out1[row] = p1; out2[row] = p2; }
    } else {
        if (lane == 0) out1[row] = p1;
    }
}

// ---------- seqpool partial (bf16 act) ----------
__global__ __launch_bounds__(256) void seqpool_partial_kernel(
    const ushort* __restrict__ act, const float* __restrict__ mask,
    float* __restrict__ partial, int S, int CH)
{
    int bc = blockIdx.x;
    int NC = S / CH;
    int b = bc / NC, c = bc - b * NC;
    int tid = threadIdx.x;
    int s0 = c * CH;
    const ushort* ab = act + ((size_t)b * S + s0) * 256;
    const float* mb = mask + b * S + s0;
    float acc = 0.f;
    for (int s = 0; s < CH; ++s)
        acc = fmaf(bf2f(ab[(size_t)s * 256 + tid]), mb[s], acc);
    partial[(size_t)bc * 256 + tid] = acc;
}

// fused: combine partials -> seqfeat + moldot, then softmax over S -> weights
__global__ __launch_bounds__(256) void seqpool_sm_kernel(
    const float* __restrict__ partial, const float* __restrict__ saW,
    const float* __restrict__ praw, const float* __restrict__ sab,
    const float* __restrict__ mask,
    float* __restrict__ seqfeat, float* __restrict__ wout, int NC, int S)
{
    int b = blockIdx.x, tid = threadIdx.x;
    int lane = tid & 63, wv = tid >> 6;
    __shared__ float red[4];
    __shared__ float sw[512];
    __shared__ float r1[4], r2[4];
    __shared__ float smd;
    float acc = 0.f;
    for (int c = 0; c < NC; ++c)
        acc += partial[((size_t)b * NC + c) * 256 + tid];
    seqfeat[b * 256 + tid] = acc;
    float am = fmaxf(acc, 0.f);
    float p = am * saW[tid];
#pragma unroll
    for (int off = 32; off > 0; off >>= 1) p += __shfl_down(p, off);
    if (lane == 0) red[wv] = p;
    __syncthreads();
    if (tid == 0) smd = red[0] + red[1] + red[2] + red[3];
    __syncthreads();
    float md = smd, sb = sab[0];
    float lm = -3.4e38f;
    for (int s = tid; s < S; s += 256) {
        float sc = md + praw[b * S + s] + sb;
        sc = sc > 0.f ? sc : 0.01f * sc;
        if (mask[b * S + s] == 0.f) sc += NEGC;
        sw[s] = sc;
        lm = fmaxf(lm, sc);
    }
#pragma unroll
    for (int off = 32; off > 0; off >>= 1) lm = fmaxf(lm, __shfl_down(lm, off));
    if (lane == 0) r1[wv] = lm;
    __syncthreads();
    float mx = fmaxf(fmaxf(r1[0], r1[1]), fmaxf(r1[2], r1[3]));
    float ls = 0.f;
    for (int s = tid; s < S; s += 256) {
        float e = __expf(sw[s] - mx);
        sw[s] = e * mask[b * S + s];
        ls += e;
    }
#pragma unroll
    for (int off = 32; off > 0; off >>= 1) ls += __shfl_down(ls, off);
    if (lane == 0) r2[wv] = ls;
    __syncthreads();
    float inv = 1.f / (r2[0] + r2[1] + r2[2] + r2[3]);
    for (int s = tid; s < S; s += 256)
        wout[b * S + s] = sw[s] * inv;
}

__global__ __launch_bounds__(256) void seqctx_partial_kernel(
    const float* __restrict__ w, const ushort* __restrict__ feat,
    float* __restrict__ partial, int S, int CH)
{
    int bc = blockIdx.x;
    int NC = S / CH;
    int b = bc / NC, c = bc - b * NC;
    int tid = threadIdx.x;
    int s0 = c * CH;
    const ushort* fb = feat + ((size_t)b * S + s0) * 256;
    const float* wb = w + b * S + s0;
    float acc = 0.f;
    for (int s = 0; s < CH; ++s)
        acc = fmaf(wb[s], bf2f(fb[(size_t)s * 256 + tid]), acc);
    partial[(size_t)bc * 256 + tid] = acc;
}

__global__ __launch_bounds__(256) void seqctx_combine_kernel(
    const float* __restrict__ partial, float* __restrict__ sctx, int NC)
{
    int b = blockIdx.x, tid = threadIdx.x;
    float acc = 0.f;
    for (int c = 0; c < NC; ++c)
        acc += partial[((size_t)b * NC + c) * 256 + tid];
    sctx[b * 256 + tid] = elu_fast(acc);
}

// sgru matmuls. full=1: both halves (j in [0,1536)); full=0: only gh (j in [768,1536))
__global__ __launch_bounds__(256) void sgru_mm_kernel(
    const float* __restrict__ x, const float* __restrict__ hseq,
    const float* __restrict__ wih, const float* __restrict__ whh,
    const float* __restrict__ bih, const float* __restrict__ bhh,
    float* __restrict__ g, int full)
{
    int per_b = full ? 1536 : 768;
    int o = blockIdx.x * 4 + (threadIdx.x >> 6);
    int lane = threadIdx.x & 63;
    int b = o / per_b;
    int j = o - b * per_b;
    if (!full) j += 768;
    const float* src; const float* w; const float* bp; int jj;
    if (j < 768) { src = x + b * 256; w = wih; bp = bih; jj = j; }
    else         { src = hseq + b * 256; w = whh; bp = bhh; jj = j - 768; }
    float p = 0.f;
#pragma unroll
    for (int i = 0; i < 4; ++i) {
        int idx = lane + 64 * i;
        p = fmaf(src[idx], w[(size_t)jj * 256 + idx], p);
    }
#pragma unroll
    for (int off = 32; off > 0; off >>= 1) p += __shfl_down(p, off);
    if (lane == 0) g[b * 1536 + j] = p + bp[jj];
}

__global__ __launch_bounds__(256) void sgru_gate_kernel(
    const float* __restrict__ g, float* __restrict__ hseq, float* __restrict__ out)
{
    int b = blockIdx.x, e = threadIdx.x;
    const float* gr = g + b * 1536;
    float r = sigm_fast(gr[e] + gr[768 + e]);
    float z = sigm_fast(gr[256 + e] + gr[1024 + e]);
    float n = tanh_fast(gr[512 + e] + r * gr[1280 + e]);
    float hv = hseq[b * 256 + e];
    float hn = (1.f - z) * n + z * hv;
    hseq[b * 256 + e] = hn;
    out[b * 256 + e] = fmaxf(hn, 0.f);
}

extern "C" void kernel_launch(void* const* d_in, const int* in_sizes, int n_in,
                              void* d_out, int out_size, void* d_ws, size_t ws_size,
                              hipStream_t stream)
{
    const float* amino   = (const float*)d_in[0];
    const int*   deg     = (const int*)  d_in[1];
    const float* mask    = (const float*)d_in[2];
    const float* embW    = (const float*)d_in[3];
    const float* embB    = (const float*)d_in[4];
    const float* neighW  = (const float*)d_in[5];
    const float* neighB  = (const float*)d_in[6];
    const float* alignW  = (const float*)d_in[7];
    const float* alignB  = (const float*)d_in[8];
    const float* attendW = (const float*)d_in[9];
    const float* attendB = (const float*)d_in[10];
    const float* gruWih  = (const float*)d_in[11];
    const float* gruWhh  = (const float*)d_in[12];
    const float* gruBih  = (const float*)d_in[13];
    const float* gruBhh  = (const float*)d_in[14];
    const float* saW     = (const float*)d_in[15];
    const float* saB     = (const float*)d_in[16];
    const float* seqAttW = (const float*)d_in[17];
    const float* seqAttB = (const float*)d_in[18];
    const float* sWih    = (const float*)d_in[19];
    const float* sWhh    = (const float*)d_in[20];
    const float* sBih    = (const float*)d_in[21];
    const float* sBhh    = (const float*)d_in[22];
    float* out = (float*)d_out;

    const int B = 32, S = 512;
    const int BS = B * S;                 // 16384
    const size_t N1 = (size_t)BS * 256;   // 4194304
    const int CH = 32, NC = S / CH;       // 16 chunks

    ushort* h_bf   = (ushort*)d_ws;              // N1 (bf16 GRU state)
    ushort* act_bf = h_bf + N1;                  // N1
    ushort* nb_bf  = act_bf + N1;                // N1 (nf round 0, then context)
    ushort* att_bf = nb_bf + N1;                 // N1 (act_t / feat_t)
    ushort* gi_bf  = att_bf + N1;                // BS*768
    ushort* gh_bf  = gi_bf + (size_t)BS * 768;
    ushort* attW_bf = gh_bf + (size_t)BS * 768;  // 3*256*256
    ushort* wih_bf  = attW_bf + 3 * 256 * 256;   // 3*768*256
    ushort* whh_bf  = wih_bf + 3 * 768 * 256;
    ushort* saW2_bf = whh_bf + 3 * 768 * 256;    // 256*256
    float* smalls = (float*)(saW2_bf + 256 * 256);
    float* ca   = smalls;            // BS
    float* cb   = ca + BS;           // BS
    float* scor = cb + BS;           // BS (raw act.saW dot)
    float* wbuf = scor + BS;         // BS
    float* seqf = wbuf + BS;         // B*256
    float* sctx = seqf + B * 256;    // B*256
    float* g    = sctx + B * 256;    // B*1536
    float* part = g + B * 1536;      // B*NC*256

    const int c0 = (3 * 256 * 256) / 4, c1 = (3 * 768 * 256) / 4,
              c2 = (3 * 768 * 256) / 4, c3 = (256 * 256) / 4;
    cvt4_kernel<<<(c0 + c1 + c2 + c3 + 255) / 256, 256, 0, stream>>>(
        attendW, attW_bf, c0, gruWih, wih_bf, c1, gruWhh, whh_bf, c2, seqAttW, saW2_bf, c3);

    embed_kernel<<<BS / 64, 256, 0, stream>>>(amino, embW, embB, neighW, neighB,
                                              h_bf, nb_bf);
    rowdots_bf16_kernel<<<BS / 4, 256, 0, stream>>>(h_bf, nb_bf, alignW, ca, cb);

    for (int d = 0; d < 3; ++d) {
        const ushort* nbr_bf = (d == 0) ? nb_bf : act_bf;
        // merged: attend-GEMM (N=256) + gh-GEMM (N=768), both ready after gate(d-1)
        gemm_dual_kernel<<<128 * 8, 256, 0, stream>>>(
            nbr_bf, attW_bf + d * 256 * 256, attendB + d * 256, att_bf, 2,
            h_bf, whh_bf + d * 768 * 256, gruBhh + d * 768, gh_bf, 6, 256);
        attn_kernel<<<BS / 4, 256, 0, stream>>>(deg, ca, cb, att_bf, alignB, d, nb_bf, S);
        gemm_dual_kernel<<<128 * 6, 256, 0, stream>>>(
            nb_bf, wih_bf + d * 768 * 256, gruBih + d * 768, gi_bf, 6,
            (const ushort*)nullptr, (const ushort*)nullptr, (const float*)nullptr,
            (ushort*)nullptr, 0, 256);
        if (d < 2) {
            gru_gate_kernel<<<BS / 4, 256, 0, stream>>>(gi_bf, gh_bf, h_bf, act_bf,
                                                        alignW + (d + 1) * 512,
                                                        alignW + (d + 1) * 512 + 256, ca, cb);
        } else {
            gru_gate_kernel<<<BS / 4, 256, 0, stream>>>(gi_bf, gh_bf, h_bf, act_bf,
                                                        saW + 256, (float*)nullptr,
                                                        scor, (float*)nullptr);
        }
    }

    seqpool_partial_kernel<<<B * NC, 256, 0, stream>>>(act_bf, mask, part, S, CH);
    gemm_dual_kernel<<<128 * 2, 256, 0, stream>>>(
        act_bf, saW2_bf, seqAttB, att_bf, 2,
        (const ushort*)nullptr, (const ushort*)nullptr, (const float*)nullptr,
        (ushort*)nullptr, 0, 256);
    seqpool_sm_kernel<<<B, 256, 0, stream>>>(part, saW, scor, saB, mask, seqf, wbuf, NC, S);
    seqctx_partial_kernel<<<B * NC, 256, 0, stream>>>(wbuf, att_bf, part, S, CH);
    seqctx_combine_kernel<<<B, 256, 0, stream>>>(part, sctx, NC);

    sgru_mm_kernel<<<B * 1536 / 4, 256, 0, stream>>>(sctx, seqf, sWih, sWhh, sBih, sBhh, g, 1);
    sgru_gate_kernel<<<B, 256, 0, stream>>>(g, seqf, out);
    sgru_mm_kernel<<<B * 768 / 4, 256, 0, stream>>>(sctx, seqf, sWih, sWhh, sBih, sBhh, g, 0);
    sgru_gate_kernel<<<B, 256, 0, stream>>>(g, seqf, out);
}